// Round 1
// baseline (1227.135 us; speedup 1.0000x reference)
//
#include <hip/hip_runtime.h>

typedef unsigned short u16;
typedef __attribute__((ext_vector_type(8))) short bf16x8;
typedef __attribute__((ext_vector_type(4))) float f32x4;

#define PITCH 40   // small-conv kernel LDS pitch (shorts)

__device__ __forceinline__ u16 f2bf(float f) {
  union { float f; unsigned u; } v; v.f = f;
  unsigned r = v.u + 0x7fffu + ((v.u >> 16) & 1u);
  return (u16)(r >> 16);
}
__device__ __forceinline__ float bf2f(u16 h) {
  union { unsigned u; float f; } v; v.u = ((unsigned)h) << 16;
  return v.f;
}
__device__ __forceinline__ float4 load4bf(const u16* p) {
  ushort4 h = *(const ushort4*)p;
  return make_float4(bf2f(h.x), bf2f(h.y), bf2f(h.z), bf2f(h.w));
}
// async global->LDS, 16B per lane; LDS dest = wave-uniform base + lane*16
__device__ __forceinline__ void gll16(const u16* g, u16* l) {
  __builtin_amdgcn_global_load_lds(
      (const __attribute__((address_space(1))) unsigned int*)g,
      (__attribute__((address_space(3))) unsigned int*)l, 16, 0, 0);
}

// ---------------- tiled transpose (l,c,s) -> token-major [(l,s), c] fp32 ----------------
__global__ __launch_bounds__(256) void k_tin(const float* __restrict__ x,
                                             float* __restrict__ xt) {
  __shared__ float t[32][33];
  int s0 = blockIdx.x * 32, c0 = blockIdx.y * 32, l = blockIdx.z;
  int r = threadIdx.x >> 3, q4 = (threadIdx.x & 7) * 4;
  float4 v = *(const float4*)(x + ((long)(l * 128 + c0 + r) << 12) + s0 + q4);
  t[r][q4] = v.x; t[r][q4 + 1] = v.y; t[r][q4 + 2] = v.z; t[r][q4 + 3] = v.w;
  __syncthreads();
  float4 o = {t[q4][r], t[q4 + 1][r], t[q4 + 2][r], t[q4 + 3][r]};
  *(float4*)(xt + ((long)(l * 4096 + s0 + r) << 7) + c0 + q4) = o;
}

__global__ __launch_bounds__(256) void k_tout(const float* __restrict__ xt,
                                              float* __restrict__ out) {
  __shared__ float t[32][33];
  int s0 = blockIdx.x * 32, c0 = blockIdx.y * 32, l = blockIdx.z;
  int r = threadIdx.x >> 3, q4 = (threadIdx.x & 7) * 4;
  float4 v = *(const float4*)(xt + ((long)(l * 4096 + s0 + r) << 7) + c0 + q4);
  t[r][q4] = v.x; t[r][q4 + 1] = v.y; t[r][q4 + 2] = v.z; t[r][q4 + 3] = v.w;
  __syncthreads();
  float4 o = {t[q4][r], t[q4 + 1][r], t[q4 + 2][r], t[q4 + 3][r]};
  *(float4*)(out + ((long)(l * 128 + c0 + r) << 12) + s0 + q4) = o;
}

__global__ __launch_bounds__(128) void k_zeropage(u16* __restrict__ zp) {
  zp[threadIdx.x] = 0;
}

// ---------------- layernorm fp32 in -> bf16 out, one wave per row ----------------
__global__ __launch_bounds__(256) void k_ln_f2b(const float* __restrict__ X,
                                                const float* __restrict__ g,
                                                const float* __restrict__ b,
                                                u16* __restrict__ Y, int M) {
  int n = blockIdx.x * 4 + (threadIdx.x >> 6);
  if (n >= M) return;
  int lane = threadIdx.x & 63;
  const float* row = X + (long)n * 128;
  float2 v = *(const float2*)(row + lane * 2);
  float s = v.x + v.y;
#pragma unroll
  for (int o = 32; o > 0; o >>= 1) s += __shfl_xor(s, o);
  float mu = s * (1.0f / 128.0f);
  float dx = v.x - mu, dy = v.y - mu;
  float q = dx * dx + dy * dy;
#pragma unroll
  for (int o = 32; o > 0; o >>= 1) q += __shfl_xor(q, o);
  float rs = rsqrtf(q * (1.0f / 128.0f) + 1e-5f);
  float2 gv = *(const float2*)(g + lane * 2);
  float2 bv = *(const float2*)(b + lane * 2);
  ushort2 o2;
  o2.x = f2bf(dx * rs * gv.x + bv.x);
  o2.y = f2bf(dy * rs * gv.y + bv.y);
  *(ushort2*)(Y + (long)n * 128 + lane * 2) = o2;
}

// ---------------- coalesced weight repack: W[oc][ic][t] fp32 -> Wb[t][oc][ic] bf16 ----------
__global__ __launch_bounds__(256) void k_repack2(const float* __restrict__ W,
                                                 u16* __restrict__ Wb,
                                                 int OC, int IC, int NT) {
  __shared__ float ws[128 * 81];
  int oc = blockIdx.x, ic0 = blockIdx.y * 128;
  const float* src = W + ((long)oc * IC + ic0) * NT;
  int n = 128 * NT;
  for (int i = threadIdx.x; i < n; i += 256) ws[i] = src[i];
  __syncthreads();
  u16* dst = Wb + (long)oc * IC + ic0;
  long tstep = (long)OC * IC;
  for (int idx = threadIdx.x; idx < n; idx += 256) {
    int t = idx >> 7, i = idx & 127;
    dst[(long)t * tstep + i] = f2bf(ws[i * NT + t]);
  }
}

// ---------------- small conv-as-gather-GEMM (64 x 64 tile) for small M ----------------
__global__ __launch_bounds__(256) void k_conv_mfma(
    const u16* __restrict__ X, const u16* __restrict__ W3,
    const float* __restrict__ bias, void* __restrict__ Yv,
    int M, int IC, int OC, int mode, int NT,
    int lgWo, int lgHo, int lgDo,
    int lgWi, int lgHi, int lgDi,
    int Li, int Di, int Hi, int Wi,
    int sL, int sD, int sH, int sW, int flags) {
  __shared__ u16 As[64 * PITCH];
  __shared__ u16 Bs[64 * PITCH];
  int tid = threadIdx.x;
  int wave = tid >> 6, lane = tid & 63;
  int quad = lane >> 4, l15 = lane & 15;
  int m0 = blockIdx.x * 64;
  int oc0 = blockIdx.y * 64;

  int srl = tid >> 2;
  int sao = (tid & 3) * 8;
  int sboc = tid >> 2, sbo = (tid & 3) * 8;

  int sm = m0 + srl;
  bool mv = sm < M;
  int w = sm & ((1 << lgWo) - 1);
  int h = (sm >> lgWo) & ((1 << lgHo) - 1);
  int d = (sm >> (lgWo + lgHo)) & ((1 << lgDo) - 1);
  int l = sm >> (lgWo + lgHo + lgDo);

  int c0 = 0, c1 = 0, c2 = 0, c3 = 0;
  auto comp_nb = [&]() -> long {
    if (!mv) return -1;
    int li, di, hi, wi; bool ok;
    if (mode == 0) {
      int dl = c0 - 1;
      int ll = (l & 1) + dl;
      ok = (ll >= 0 && ll < 2);
      li = l + dl; di = d; hi = h; wi = w;
    } else if (mode == 1) {
      li = l * sL; di = d * sD + c2 - 1; hi = h * sH + c1 - 1; wi = w * sW + c0 - 1;
      ok = ((unsigned)di < (unsigned)Di) && ((unsigned)hi < (unsigned)Hi) &&
           ((unsigned)wi < (unsigned)Wi);
    } else {
      li = l + c3 - 1; di = d + c2 - 1; hi = h + c1 - 1; wi = w + c0 - 1;
      ok = ((unsigned)li < (unsigned)Li) && ((unsigned)di < (unsigned)Di) &&
           ((unsigned)hi < (unsigned)Hi) && ((unsigned)wi < (unsigned)Wi);
    }
    if (!ok) return -1;
    return ((((long)((li << lgDi) + di) << lgHi) + hi) << lgWi) + wi;
  };

  long nb = comp_nb();
  const u16* wt = W3 + (long)(oc0 + sboc) * IC + sbo;
  long wstep = (long)OC * IC;
  int kmask = (IC >> 5) - 1;
  int total = NT * (IC >> 5);

  const bf16x8 Z = {0, 0, 0, 0, 0, 0, 0, 0};
  bf16x8 ra0 = Z, rb;
  if (nb >= 0) ra0 = *(const bf16x8*)(X + nb * IC + sao);
  rb = *(const bf16x8*)wt;

  f32x4 acc[4];
#pragma unroll
  for (int j = 0; j < 4; ++j) acc[j] = {0.f, 0.f, 0.f, 0.f};

  int wrow = wave * 16;

  for (int ks = 0; ks < total; ++ks) {
    __syncthreads();
    *(bf16x8*)&As[srl * PITCH + sao] = ra0;
    *(bf16x8*)&Bs[sboc * PITCH + sbo] = rb;
    __syncthreads();
    int ksn = ks + 1;
    if (ksn < total) {
      int k0n = (ksn & kmask) << 5;
      if ((ksn & kmask) == 0) {
        wt += wstep;
        if (++c0 == 3) { c0 = 0; if (++c1 == 3) { c1 = 0; if (++c2 == 3) { c2 = 0; ++c3; } } }
        nb = comp_nb();
      }
      ra0 = Z;
      if (nb >= 0) ra0 = *(const bf16x8*)(X + nb * IC + k0n + sao);
      rb = *(const bf16x8*)(wt + k0n);
    }
    bf16x8 a0 = *(const bf16x8*)&As[(wrow + l15) * PITCH + quad * 8];
#pragma unroll
    for (int j = 0; j < 4; ++j) {
      bf16x8 b = *(const bf16x8*)&Bs[(j * 16 + l15) * PITCH + quad * 8];
      acc[j] = __builtin_amdgcn_mfma_f32_16x16x32_bf16(a0, b, acc[j], 0, 0, 0);
    }
  }

  int col = oc0 + l15;
#pragma unroll
  for (int j = 0; j < 4; ++j) {
    float bj = bias[col + j * 16];
    int rbase = m0 + wrow + quad * 4;
#pragma unroll
    for (int r = 0; r < 4; ++r) {
      int row = rbase + r;
      if (row >= M) continue;
      float v = acc[j][r] + bj;
      if (flags & 2) v = fmaxf(v, 0.f);
      long off = (long)row * OC + col + j * 16;
      if (flags & 4) ((u16*)Yv)[off] = f2bf(v);
      else if (flags & 1) ((float*)Yv)[off] += v;
      else ((float*)Yv)[off] = v;
    }
  }
}

// ---------------- big conv-GEMM: 128x128 tile, BK=64, single-buffer global_load_lds ----------
__global__ __launch_bounds__(256, 4) void k_conv_gl(
    const u16* __restrict__ X, const u16* __restrict__ W3,
    const float* __restrict__ bias, void* __restrict__ Yv, float* __restrict__ SP,
    const u16* __restrict__ ZP,
    int M, int IC, int OC, int mode, int NT, int NSPLIT,
    int lgWo, int lgHo, int lgDo,
    int lgWi, int lgHi, int lgDi,
    int Li, int Di, int Hi, int Wi,
    int sL, int sD, int sH, int sW, int flags) {
  __shared__ __align__(16) u16 As[128 * 64];
  __shared__ __align__(16) u16 Bs[128 * 64];
  int tid = threadIdx.x;
  int wave = tid >> 6, lane = tid & 63;
  int quad = lane >> 4, l15 = lane & 15;
  int m0 = blockIdx.x * 128, oc0 = blockIdx.y * 128;
  int mi = wave & 1, ni = wave >> 1;

  int rp[4], cA[4], sm[4];
#pragma unroll
  for (int q = 0; q < 4; ++q) {
    rp[q] = wave * 32 + q * 8 + (lane >> 3);
    cA[q] = ((lane & 7) - (rp[q] >> 1)) & 7;
    sm[q] = m0 + rp[q];
  }

  int tap_per = (NT + NSPLIT - 1) / NSPLIT;
  int t0 = blockIdx.z * tap_per;
  int t1 = min(NT, t0 + tap_per);
  int kc = IC >> 6;
  int total = (t1 - t0) * kc;

  int c0 = t0 % 3, c1 = (t0 / 3) % 3, c2 = (t0 / 9) % 3, c3 = t0 / 27;
  auto comp_nb = [&](int smv) -> int {
    if (smv >= M) return -1;
    int w = smv & ((1 << lgWo) - 1);
    int h = (smv >> lgWo) & ((1 << lgHo) - 1);
    int d = (smv >> (lgWo + lgHo)) & ((1 << lgDo) - 1);
    int l = smv >> (lgWo + lgHo + lgDo);
    int li, di, hi, wi; bool ok;
    if (mode == 0) {
      int dl = c0 - 1;
      int ll = (l & 1) + dl;
      ok = (ll >= 0 && ll < 2);
      li = l + dl; di = d; hi = h; wi = w;
    } else if (mode == 1) {
      li = l * sL; di = d * sD + c2 - 1; hi = h * sH + c1 - 1; wi = w * sW + c0 - 1;
      ok = ((unsigned)di < (unsigned)Di) && ((unsigned)hi < (unsigned)Hi) &&
           ((unsigned)wi < (unsigned)Wi);
    } else {
      li = l + c3 - 1; di = d + c2 - 1; hi = h + c1 - 1; wi = w + c0 - 1;
      ok = ((unsigned)li < (unsigned)Li) && ((unsigned)di < (unsigned)Di) &&
           ((unsigned)hi < (unsigned)Hi) && ((unsigned)wi < (unsigned)Wi);
    }
    if (!ok) return -1;
    return (((li << lgDi) + di) << lgHi | hi) << lgWi | wi;
  };

  int nb[4];
#pragma unroll
  for (int q = 0; q < 4; ++q) nb[q] = comp_nb(sm[q]);
  long wstep = (long)OC * IC;
  const u16* wbase = W3 + (long)t0 * wstep + (long)oc0 * IC;

  f32x4 acc[4][4];
#pragma unroll
  for (int i = 0; i < 4; ++i)
#pragma unroll
    for (int j = 0; j < 4; ++j) acc[i][j] = {0.f, 0.f, 0.f, 0.f};

  int kk = 0;
  for (int ks = 0; ks < total; ++ks) {
    if (kk == kc) {
      kk = 0;
      if (++c0 == 3) { c0 = 0; if (++c1 == 3) { c1 = 0; if (++c2 == 3) { c2 = 0; ++c3; } } }
#pragma unroll
      for (int q = 0; q < 4; ++q) nb[q] = comp_nb(sm[q]);
      wbase += wstep;
    }
    int k0 = kk << 6;
    ++kk;
    __syncthreads();
#pragma unroll
    for (int q = 0; q < 4; ++q) {
      const u16* a = (nb[q] >= 0) ? X + (long)nb[q] * IC + k0 + cA[q] * 8 : ZP;
      gll16(a, &As[(wave * 4 + q) * 512]);
    }
#pragma unroll
    for (int q = 0; q < 4; ++q) {
      const u16* bsrc = wbase + (long)rp[q] * IC + k0 + cA[q] * 8;
      gll16(bsrc, &Bs[(wave * 4 + q) * 512]);
    }
    __syncthreads();
#pragma unroll
    for (int ksub = 0; ksub < 2; ++ksub) {
      bf16x8 af[4], bf[4];
#pragma unroll
      for (int i = 0; i < 4; ++i) {
        int row = mi * 64 + i * 16 + l15;
        int pa = ((ksub * 4 + quad) + (row >> 1)) & 7;
        af[i] = *(const bf16x8*)&As[row * 64 + pa * 8];
      }
#pragma unroll
      for (int j = 0; j < 4; ++j) {
        int row = ni * 64 + j * 16 + l15;
        int pb = ((ksub * 4 + quad) + (row >> 1)) & 7;
        bf[j] = *(const bf16x8*)&Bs[row * 64 + pb * 8];
      }
#pragma unroll
      for (int i = 0; i < 4; ++i)
#pragma unroll
        for (int j = 0; j < 4; ++j)
          acc[i][j] = __builtin_amdgcn_mfma_f32_16x16x32_bf16(af[i], bf[j], acc[i][j], 0, 0, 0);
    }
  }

  if (NSPLIT > 1) {
    float* out = SP + (long)blockIdx.z * M * OC;
#pragma unroll
    for (int j = 0; j < 4; ++j) {
      int c = oc0 + ni * 64 + j * 16 + l15;
#pragma unroll
      for (int i = 0; i < 4; ++i) {
        int rbase = m0 + mi * 64 + i * 16 + quad * 4;
#pragma unroll
        for (int r = 0; r < 4; ++r) {
          int row = rbase + r;
          if (row < M) out[(long)row * OC + c] = acc[i][j][r];
        }
      }
    }
  } else {
#pragma unroll
    for (int j = 0; j < 4; ++j) {
      int c = oc0 + ni * 64 + j * 16 + l15;
      float bj = bias[c];
#pragma unroll
      for (int i = 0; i < 4; ++i) {
        int rbase = m0 + mi * 64 + i * 16 + quad * 4;
#pragma unroll
        for (int r = 0; r < 4; ++r) {
          int row = rbase + r;
          if (row >= M) continue;
          float v = acc[i][j][r] + bj;
          if (flags & 2) v = fmaxf(v, 0.f);
          long off = (long)row * OC + c;
          if (flags & 4) ((u16*)Yv)[off] = f2bf(v);
          else if (flags & 1) ((float*)Yv)[off] += v;
          else ((float*)Yv)[off] = v;
        }
      }
    }
  }
}

// ---------------- 256x256 8-phase conv-GEMM (T2+T3+T4+T5), BK=64, 8 waves ----------------
// LDS halves split along K: per (dbuf, khalf) region = [256 rows][32 shorts].
// Phase p in {0..3}: ksub = p>>1, i-half = p&1. 16 MFMA/phase, 2 gll16/thread/phase,
// raw s_barrier + counted vmcnt(8) (never 0 in loop). Out-of-range prefetch -> zero page
// so vmcnt accounting stays uniform. Chunk swizzle: phys = (logical + row>>1) & 3,
// applied on global SOURCE (linear gll16 dest) and on ds_read address.
__global__ __launch_bounds__(512, 2) void k_conv_g256(
    const u16* __restrict__ X, const u16* __restrict__ W3,
    const float* __restrict__ bias, void* __restrict__ Yv, float* __restrict__ SP,
    const u16* __restrict__ ZP,
    int M, int IC, int OC, int mode, int NT, int NSPLIT,
    int lgWo, int lgHo, int lgDo,
    int lgWi, int lgHi, int lgDi,
    int Li, int Di, int Hi, int Wi,
    int sL, int sD, int sH, int sW, int flags) {
  __shared__ __align__(16) u16 Ab[2][2][8192];   // 64 KiB
  __shared__ __align__(16) u16 Bb[2][2][8192];   // 64 KiB
  int tid = threadIdx.x;
  int wave = tid >> 6, lane = tid & 63;
  int quad = lane >> 4, l15 = lane & 15;
  int wr = wave >> 2, wc = wave & 3;
  int m0 = blockIdx.x * 256, oc0 = blockIdx.y * 256;

  // staging: thread covers rows srow0 (issue 0) and srow1 (issue 1), 16B chunk spc
  int srow0 = tid >> 2, srow1 = 128 + (tid >> 2);
  int spc = tid & 3;
  int lc0 = (spc - (srow0 >> 1)) & 3;   // logical k-chunk stored at this slot
  int lc1 = (spc - (srow1 >> 1)) & 3;

  int kc = IC >> 6;
  int lgkc = 31 - __builtin_clz(kc);
  int kcm = kc - 1;
  int tap_per = (NT + NSPLIT - 1) / NSPLIT;
  int t0 = blockIdx.z * tap_per;
  int t1 = min(NT, t0 + tap_per);
  int TOT = (t1 - t0) * kc;

  int c0 = t0 % 3, c1 = (t0 / 3) % 3, c2 = (t0 / 9) % 3, c3 = t0 / 27;
  auto comp_nb = [&](int smv) -> int {
    if (smv >= M) return -1;
    int w = smv & ((1 << lgWo) - 1);
    int h = (smv >> lgWo) & ((1 << lgHo) - 1);
    int d = (smv >> (lgWo + lgHo)) & ((1 << lgDo) - 1);
    int l = smv >> (lgWo + lgHo + lgDo);
    int li, di, hi, wi; bool ok;
    if (mode == 0) {
      int dl = c0 - 1;
      int ll = (l & 1) + dl;
      ok = (ll >= 0 && ll < 2);
      li = l + dl; di = d; hi = h; wi = w;
    } else if (mode == 1) {
      li = l * sL; di = d * sD + c2 - 1; hi = h * sH + c1 - 1; wi = w * sW + c0 - 1;
      ok = ((unsigned)di < (unsigned)Di) && ((unsigned)hi < (unsigned)Hi) &&
           ((unsigned)wi < (unsigned)Wi);
    } else {
      li = l + c3 - 1; di = d + c2 - 1; hi = h + c1 - 1; wi = w + c0 - 1;
      ok = ((unsigned)li < (unsigned)Li) && ((unsigned)di < (unsigned)Di) &&
           ((unsigned)hi < (unsigned)Hi) && ((unsigned)wi < (unsigned)Wi);
    }
    if (!ok) return -1;
    return (((li << lgDi) + di) << lgHi | hi) << lgWi | wi;
  };

  // rolling A-gather state; stage calls are monotone in tile index
  int atap = 0;
  int nb0 = comp_nb(m0 + srow0);
  int nb1 = comp_nb(m0 + srow1);
  auto advA = [&](int kt) {
    int tp = kt >> lgkc;
    while (atap < tp) {
      ++atap;
      if (++c0 == 3) { c0 = 0; if (++c1 == 3) { c1 = 0; if (++c2 == 3) { c2 = 0; ++c3; } } }
      nb0 = comp_nb(m0 + srow0);
      nb1 = comp_nb(m0 + srow1);
    }
  };
  auto stageA = [&](int kt, int ks) {
    u16* dst = &Ab[kt & 1][ks][wave << 9];
    if (kt >= TOT) { gll16(ZP, dst); gll16(ZP, dst + 4096); return; }
    advA(kt);
    int kb = ((kt & kcm) << 6) + (ks << 5);
    const u16* s0 = (nb0 >= 0) ? X + (long)nb0 * IC + kb + lc0 * 8 : ZP;
    const u16* s1 = (nb1 >= 0) ? X + (long)nb1 * IC + kb + lc1 * 8 : ZP;
    gll16(s0, dst);
    gll16(s1, dst + 4096);
  };
  auto stageB = [&](int kt, int ks) {
    u16* dst = &Bb[kt & 1][ks][wave << 9];
    if (kt >= TOT) { gll16(ZP, dst); gll16(ZP, dst + 4096); return; }
    int kb = ((kt & kcm) << 6) + (ks << 5);
    const u16* wp = W3 + ((long)(t0 + (kt >> lgkc)) * OC + oc0) * IC + kb;
    gll16(wp + (long)srow0 * IC + lc0 * 8, dst);
    gll16(wp + (long)srow1 * IC + lc1 * 8, dst + 4096);
  };

  f32x4 acc[8][4];
#pragma unroll
  for (int i = 0; i < 8; ++i)
#pragma unroll
    for (int j = 0; j < 4; ++j) acc[i][j] = {0.f, 0.f, 0.f, 0.f};

  bf16x8 af[4], bfr[4];
  auto rdA = [&](int buf, int ks, int ih) {
#pragma unroll
    for (int i = 0; i < 4; ++i) {
      int row = (wr << 7) + (ih << 6) + (i << 4) + l15;
      int pc = (quad + (row >> 1)) & 3;
      af[i] = *(const bf16x8*)&Ab[buf][ks][row * 32 + pc * 8];
    }
  };
  auto rdB = [&](int buf, int ks) {
#pragma unroll
    for (int j = 0; j < 4; ++j) {
      int row = (wc << 6) + (j << 4) + l15;
      int pc = (quad + (row >> 1)) & 3;
      bfr[j] = *(const bf16x8*)&Bb[buf][ks][row * 32 + pc * 8];
    }
  };
  auto mf = [&](int ih) {
    __builtin_amdgcn_s_setprio(1);
#pragma unroll
    for (int i = 0; i < 4; ++i)
#pragma unroll
      for (int j = 0; j < 4; ++j)
        acc[(ih << 2) + i][j] =
            __builtin_amdgcn_mfma_f32_16x16x32_bf16(af[i], bfr[j], acc[(ih << 2) + i][j], 0, 0, 0);
    __builtin_amdgcn_s_setprio(0);
  };

  // prologue: A/B(0,k0), A/B(0,k1), A/B(1,k0) -> 12 loads; keep last 8 in flight
  stageA(0, 0); stageB(0, 0);
  stageA(0, 1); stageB(0, 1);
  stageA(1, 0); stageB(1, 0);
  asm volatile("s_waitcnt vmcnt(8)" ::: "memory");
  __builtin_amdgcn_s_barrier();

  for (int n = 0; n < TOT; ++n) {
    int buf = n & 1;
    // phase 0: ksub0, i-half0
    rdA(buf, 0, 0); rdB(buf, 0);
    stageA(n + 1, 1);
    __builtin_amdgcn_s_barrier();
    mf(0);
    __builtin_amdgcn_s_barrier();
    // phase 1: ksub0, i-half1 (B reused from regs)
    rdA(buf, 0, 1);
    stageB(n + 1, 1);
    __builtin_amdgcn_s_barrier();
    mf(1);
    asm volatile("s_waitcnt vmcnt(8)" ::: "memory");
    __builtin_amdgcn_s_barrier();
    // phase 2: ksub1, i-half0
    rdA(buf, 1, 0); rdB(buf, 1);
    stageA(n + 2, 0);
    __builtin_amdgcn_s_barrier();
    mf(0);
    __builtin_amdgcn_s_barrier();
    // phase 3: ksub1, i-half1
    rdA(buf, 1, 1);
    stageB(n + 2, 0);
    __builtin_amdgcn_s_barrier();
    mf(1);
    asm volatile("s_waitcnt vmcnt(8)" ::: "memory");
    __builtin_amdgcn_s_barrier();
  }

  // epilogue: C/D layout col=l15, row=quad*4+r
  if (NSPLIT > 1) {
    float* outp = SP + (long)blockIdx.z * M * OC;
#pragma unroll
    for (int i = 0; i < 8; ++i)
#pragma unroll
      for (int j = 0; j < 4; ++j) {
        int c = oc0 + (wc << 6) + (j << 4) + l15;
        int rb = m0 + (wr << 7) + (i << 4) + (quad << 2);
#pragma unroll
        for (int r = 0; r < 4; ++r) {
          int row = rb + r;
          if (row < M) outp[(long)row * OC + c] = acc[i][j][r];
        }
      }
  } else {
#pragma unroll
    for (int i = 0; i < 8; ++i)
#pragma unroll
      for (int j = 0; j < 4; ++j) {
        int c = oc0 + (wc << 6) + (j << 4) + l15;
        float bj = bias[c];
        int rb = m0 + (wr << 7) + (i << 4) + (quad << 2);
#pragma unroll
        for (int r = 0; r < 4; ++r) {
          int row = rb + r;
          if (row >= M) continue;
          float v = acc[i][j][r] + bj;
          if (flags & 2) v = fmaxf(v, 0.f);
          long off = (long)row * OC + c;
          if (flags & 4) ((u16*)Yv)[off] = f2bf(v);
          else if (flags & 1) ((float*)Yv)[off] += v;
          else ((float*)Yv)[off] = v;
        }
      }
  }
}

// ---------------- combine split-K partials: out = (sum_s SP[s]) + bias ----------------
__global__ __launch_bounds__(256) void k_combine(const float* __restrict__ SP,
                                                 const float* __restrict__ bias,
                                                 void* __restrict__ out,
                                                 long MOC, int lgOC, int nsplit, int flags) {
  long idx = (long)blockIdx.x * 256 + threadIdx.x;
  if (idx >= MOC) return;
  float v = bias[idx & ((1 << lgOC) - 1)];
  for (int s = 0; s < nsplit; ++s) v += SP[s * MOC + idx];
  if (flags & 2) v = fmaxf(v, 0.f);
  if (flags & 4) ((u16*)out)[idx] = f2bf(v);
  else if (flags & 1) ((float*)out)[idx] += v;
  else ((float*)out)[idx] = v;
}

// ---------------- TLG windowed cross attention: 8q x 8k per (window, head), bf16 ----------------
__global__ __launch_bounds__(256) void k_tlg_attn(const u16* __restrict__ Q,
                                                  const u16* __restrict__ K,
                                                  const u16* __restrict__ V,
                                                  u16* __restrict__ Y) {
  int gw = blockIdx.x * 4 + (threadIdx.x >> 6);
  int lane = threadIdx.x & 63;
  int head = gw & 7;
  int win = gw >> 3;
  int wB = win & 7, hB = (win >> 3) & 7, dB = (win >> 6) & 7, l = win >> 9;
  int i = lane >> 3, j = lane & 7;
  int nq = (l << 12) | ((dB * 2 + (i >> 2)) << 8) | ((hB * 2 + ((i >> 1) & 1)) << 4) |
           (wB * 2 + (i & 1));
  int lk = l ^ 2;
  int nk = (lk << 12) | ((dB * 2 + (j >> 2)) << 8) | ((hB * 2 + ((j >> 1) & 1)) << 4) |
           (wB * 2 + (j & 1));
  int hoff = head * 16;
  const u16* qp = Q + (long)nq * 128 + hoff;
  const u16* kp = K + (long)nk * 128 + hoff;
  float s = 0.f;
#pragma unroll
  for (int t = 0; t < 16; t += 4) {
    float4 a = load4bf(qp + t);
    float4 b = load4bf(kp + t);
    s += a.x * b.x + a.y * b.y + a.z * b.z + a.w * b.w;
  }
  s *= 0.25f;
  float mx = s;
#pragma unroll
  for (int o = 1; o < 8; o <<= 1) mx = fmaxf(mx, __shfl_xor(mx, o));
  float e = __expf(s - mx);
  float sum = e;
#pragma unroll
  for (int o = 1; o < 8; o <<= 1) sum += __shfl_xor(sum, o);
  float p = e / sum;
  const u16* vp = V + (long)nk * 128 + hoff;
  float y[16];
#pragma unroll
  for (int t = 0; t < 16; t += 4) {
    float4 vv = load4bf(vp + t);
    y[t] = p * vv.x; y[t + 1] = p * vv.y; y[t + 2] = p * vv.z; y[t + 3] = p * vv.w;
  }
#pragma unroll
  for (int o = 1; o < 8; o <<= 1) {
#pragma unroll
    for (int t = 0; t < 16; ++t) y[t] += __shfl_xor(y[t], o);
  }
  if (j == 0) {
    u16* yp = Y + (long)nq * 128 + hoff;
    u16 tmp[16];
#pragma unroll
    for (int t = 0; t < 16; ++t) tmp[t] = f2bf(y[t]);
    *(uint4*)(yp) = *(uint4*)tmp;
    *(uint4*)(yp + 8) = *(uint4*)(tmp + 8);
  }
}

// ---------------- SLG K/V repack for flash attn ----------------
__global__ __launch_bounds__(256) void k_pack_kh(const u16* __restrict__ Kin,
                                                 u16* __restrict__ Kh) {
  int idx = blockIdx.x * 256 + threadIdx.x;
  if (idx >= 8 * 1032 * 16) return;
  int d = idx & 15;
  int r = idx >> 4;
  int k = r % 1032, h = r / 1032;
  Kh[idx] = Kin[k * 128 + h * 16 + d];
}
__global__ __launch_bounds__(256) void k_pack_vt(const u16* __restrict__ Vin,
                                                 u16* __restrict__ Vt) {
  int idx = blockIdx.x * 256 + threadIdx.x;
  if (idx >= 8 * 16 * 1032) return;
  int k = idx % 1032;
  int r = idx / 1032;
  int d = r & 15, h = r >> 4;
  Vt[idx] = Vin[k * 128 + h * 16 + d];
}

// ---------------- SLG MFMA flash attention ----------------
__global__ __launch_bounds__(256) void k_slg_flash(const u16* __restrict__ Q,
                                                   const u16* __restrict__ Kh,
                                                   const u16* __restrict__ Vt,
                                                   u16* __restrict__ Y) {
  constexpr int NK = 1032;
  constexpr int NTILE = 17;
  __shared__ __align__(16) u16 Ks[64 * 24];
  __shared__ __align__(16) u16 Vs[16 * 72];
  __shared__ __align__(16) u16 Ps[4][16 * 72];
  int tid = threadIdx.x;
  int wave = tid >> 6, lane = tid & 63;
  int quad = lane >> 4, l15 = lane & 15;
  int h = blockIdx.x & 7;
  int q0 = (blockIdx.x >> 3) * 64 + wave * 16;

  const bf16x8 Zb = {0, 0, 0, 0, 0, 0, 0, 0};
  bf16x8 qf = Zb;
  if (quad < 2) qf = *(const bf16x8*)(Q + (long)(q0 + l15) * 128 + h * 16 + quad * 8);

  const u16* Kbase = Kh + (long)h * NK * 16;
  const u16* Vbase = Vt + (long)h * 16 * NK;

  float mrow[4], lrow[4];
  f32x4 oacc = {0.f, 0.f, 0.f, 0.f};
#pragma unroll
  for (int r = 0; r < 4; ++r) { mrow[r] = -1e30f; lrow[r] = 0.f; }

  int skey = tid >> 2, sch = (tid & 3) * 4;
  int svd = tid >> 4, svc = (tid & 15) * 4;

  for (int t = 0; t < NTILE; ++t) {
    int k0 = t * 64;
    __syncthreads();
    {
      short4 v = {0, 0, 0, 0};
      int key = k0 + skey;
      if (key < NK) v = *(const short4*)(Kbase + key * 16 + sch);
      *(short4*)&Ks[skey * 24 + sch] = v;
    }
    {
      short4 v = {0, 0, 0, 0};
      int colb = k0 + svc;
      if (colb < NK) v = *(const short4*)(Vbase + svd * NK + colb);
      *(short4*)&Vs[svd * 72 + svc] = v;
    }
    __syncthreads();

    f32x4 s[4];
#pragma unroll
    for (int sub = 0; sub < 4; ++sub) {
      bf16x8 b = Zb;
      if (quad < 2) b = *(const bf16x8*)&Ks[(sub * 16 + l15) * 24 + quad * 8];
      f32x4 zero = {0.f, 0.f, 0.f, 0.f};
      s[sub] = __builtin_amdgcn_mfma_f32_16x16x32_bf16(qf, b, zero, 0, 0, 0);
    }
    float pv[4][4];
    float tmax[4] = {-1e30f, -1e30f, -1e30f, -1e30f};
#pragma unroll
    for (int sub = 0; sub < 4; ++sub) {
      int key = k0 + sub * 16 + l15;
      bool valid = key < NK;
#pragma unroll
      for (int r = 0; r < 4; ++r) {
        float sv = valid ? s[sub][r] * 0.25f : -1e30f;
        pv[sub][r] = sv;
        tmax[r] = fmaxf(tmax[r], sv);
      }
    }
#pragma unroll
    for (int o = 1; o < 16; o <<= 1)
#pragma unroll
      for (int r = 0; r < 4; ++r) tmax[r] = fmaxf(tmax[r], __shfl_xor(tmax[r], o));

    float al[4], tsum[4] = {0.f, 0.f, 0.f, 0.f};
#pragma unroll
    for (int r = 0; r < 4; ++r) {
      float mn = fmaxf(mrow[r], tmax[r]);
      al[r] = __expf(mrow[r] - mn);
      mrow[r] = mn;
    }
#pragma unroll
    for (int sub = 0; sub < 4; ++sub)
#pragma unroll
      for (int r = 0; r < 4; ++r) {
        float pe = __expf(pv[sub][r] - mrow[r]);
        tsum[r] += pe;
        Ps[wave][(quad * 4 + r) * 72 + sub * 16 + l15] = f2bf(pe);
      }
#pragma unroll
    for (int o = 1; o < 16; o <<= 1)
#pragma unroll
      for (int r = 0; r < 4; ++r) tsum[r] += __shfl_xor(tsum[r], o);
#pragma unroll
    for (int r = 0; r < 4; ++r) {
      lrow[r] = lrow[r] * al[r] + tsum[r];
      oacc[r] *= al[r];
    }
    bf16x8 pa0 = *(const bf16x8*)&Ps[wave][l15 * 72 + quad * 8];
    bf16x8 pa1 = *(const bf16x8*)&Ps[wave][l15 * 72 + 32 + quad * 8];
    bf16x8 vb0 = *(const bf16x8*)&Vs[l15 * 72 + quad * 8];
    bf16x8 vb1 = *(const bf16x8*)&Vs[l15 * 72 + 32 + quad * 8];
    oacc = __builtin_amdgcn_mfma_f32_16x16x32_bf16(pa0, vb0, oacc, 0, 0, 0);
    oacc = __builtin_amdgcn_mfma_f32_16x16x32_bf16(pa1, vb1, oacc, 0, 0, 0);
  }

#pragma unroll
  for (int r = 0; r < 4; ++r) {
    float inv = 1.0f / lrow[r];
    Y[(long)(q0 + quad * 4 + r) * 128 + h * 16 + l15] = f2bf(oacc[r] * inv);
  }
}

static inline int ilg(int v) { int r = 0; while ((1 << r) < v) ++r; return r; }

extern "C" void kernel_launch(void* const* d_in, const int* in_sizes, int n_in,
                              void* d_out, int out_size, void* d_ws, size_t ws_size,
                              hipStream_t stream) {
  (void)in_sizes; (void)n_in; (void)out_size; (void)ws_size;
  const float* x    = (const float*)d_in[0];
  const float* n1_w = (const float*)d_in[1];  const float* n1_b = (const float*)d_in[2];
  const float* n2_w = (const float*)d_in[3];  const float* n2_b = (const float*)d_in[4];
  const float* n3_w = (const float*)d_in[5];  const float* n3_b = (const float*)d_in[6];
  const float* sn_w = (const float*)d_in[7];  const float* sn_b = (const float*)d_in[8];
  const float* tq_w = (const float*)d_in[9];  const float* tq_b = (const float*)d_in[10];
  const float* tk_w = (const float*)d_in[11]; const float* tk_b = (const float*)d_in[12];
  const float* tv_w = (const float*)d_in[13]; const float* tv_b = (const float*)d_in[14];
  const float* tp_w = (const float*)d_in[15]; const float* tp_b = (const float*)d_in[16];
  const float* sq_w = (const float*)d_in[17]; const float* sq_b = (const float*)d_in[18];
  const float* sk_w = (const float*)d_in[19]; const float* sk_b = (const float*)d_in[20];
  const float* sv_w = (const float*)d_in[21]; const float* sv_b = (const float*)d_in[22];
  const float* sp_w = (const float*)d_in[23]; const float* sp_b = (const float*)d_in[24];
  const float* sf_w = (const float*)d_in[25]; const float* sf_b = (const float*)d_in[26];
  const float* sc_w = (const float*)d_in[27]; const float* sc_b = (const float*)d_in[28];
  const float* m1_w = (const float*)d_in[29]; const float* m1_b = (const float*)d_in[30];
  const float* m2_w = (const float*)d_in[31]; const float* m2_b = (const float*)d_in[32];

  char* p = (char*)d_ws;
  auto alloc = [&](size_t bytes) { char* r = p; p += (bytes + 255) & ~(size_t)255; return r; };
  const long N = 16384;
  float* X0 = (float*)alloc(N * 128 * 4);
  u16* XN = (u16*)alloc(N * 128 * 2);
  u16* Qb = (u16*)alloc(N * 128 * 2);
  u16* Kb = (u16*)alloc(N * 128 * 2);
  u16* Vb = (u16*)alloc(N * 128 * 2);
  u16* Yb = (u16*)alloc(N * 128 * 2);
  u16* H  = (u16*)alloc(N * 512 * 2);
  u16* XC = (u16*)alloc(8 * 128 * 2);
  u16* XF = (u16*)alloc(1024 * 128 * 2);
  float* Kf = (float*)alloc(1032 * 128 * 4);
  float* Vf = (float*)alloc(1032 * 128 * 4);
  u16* Kh = (u16*)alloc(8 * 1032 * 16 * 2);
  u16* Vt = (u16*)alloc(8 * 16 * 1032 * 2);
  float* SPb = (float*)alloc(2L * N * 512 * 4);  // split-K partials (64 MB)
  u16* ZPb = (u16*)alloc(256);                    // zero page for masked gather rows
  u16* tq2 = (u16*)alloc(49152 * 2);  u16* tk2 = (u16*)alloc(49152 * 2);
  u16* tv2 = (u16*)alloc(49152 * 2);  u16* tp2 = (u16*)alloc(49152 * 2);
  u16* sq2 = (u16*)alloc(442368 * 2); u16* sk2 = (u16*)alloc(442368 * 2);
  u16* sv2 = (u16*)alloc(442368 * 2); u16* sp2 = (u16*)alloc(442368 * 2);
  u16* sf2 = (u16*)alloc(442368 * 2); u16* sc2 = (u16*)alloc(442368 * 2);
  u16* m12 = (u16*)alloc(5308416L * 2);
  u16* m22 = (u16*)alloc(5308416L * 2);

  k_zeropage<<<1, 128, 0, stream>>>(ZPb);

  auto rp = [&](const float* W, u16* Wb, int OC, int IC, int NT) {
    dim3 g(OC, IC / 128);
    k_repack2<<<g, 256, 0, stream>>>(W, Wb, OC, IC, NT);
  };
  rp(tq_w, tq2, 128, 128, 3);  rp(tk_w, tk2, 128, 128, 3);
  rp(tv_w, tv2, 128, 128, 3);  rp(tp_w, tp2, 128, 128, 3);
  rp(sq_w, sq2, 128, 128, 27); rp(sk_w, sk2, 128, 128, 27);
  rp(sv_w, sv2, 128, 128, 27); rp(sp_w, sp2, 128, 128, 27);
  rp(sf_w, sf2, 128, 128, 27); rp(sc_w, sc2, 128, 128, 27);
  rp(m1_w, m12, 512, 128, 81); rp(m2_w, m22, 128, 512, 81);

  auto conv = [&](const u16* Xp, const u16* Wp, const float* Bp, void* Yp,
                  int M, int IC, int OC, int mode, int NT,
                  int Do, int Ho, int Wo, int Li, int Di, int Hi, int Wi,
                  int sL, int sD, int sH, int sW, int flags) {
    int lgWo = ilg(Wo), lgHo = ilg(Ho), lgDo = ilg(Do);
    int lgWi = ilg(Wi), lgHi = ilg(Hi), lgDi = ilg(Di);
    dim3 g((M + 63) / 64, OC / 64);
    k_conv_mfma<<<g, 256, 0, stream>>>(Xp, Wp, Bp, Yp, M, IC, OC, mode, NT,
                                       lgWo, lgHo, lgDo, lgWi, lgHi, lgDi,
                                       Li, Di, Hi, Wi, sL, sD, sH, sW, flags);
  };
  auto conv_gl = [&](const u16* Xp, const u16* Wp, const float* Bp, void* Yp,
                     int M, int IC, int OC, int mode, int NT, int nsplit, int flags) {
    dim3 g(M / 128, OC / 128, nsplit);
    k_conv_gl<<<g, 256, 0, stream>>>(Xp, Wp, Bp, Yp, SPb, ZPb, M, IC, OC, mode, NT, nsplit,
                                     4, 4, 4, 4, 4, 4, 4, 16, 16, 16, 1, 1, 1, 1, flags);
    if (nsplit > 1) {
      long MOC = (long)M * OC;
      k_combine<<<(int)((MOC + 255) / 256), 256, 0, stream>>>(SPb, Bp, Yp, MOC, ilg(OC),
                                                              nsplit, flags);
    }
  };
  // 256x256 8-phase kernel (needs M%256==0 and OC%256==0)
  auto conv_gl256 = [&](const u16* Xp, const u16* Wp, const float* Bp, void* Yp,
                        int M, int IC, int OC, int mode, int NT, int nsplit, int flags) {
    dim3 g(M / 256, OC / 256, nsplit);
    k_conv_g256<<<g, 512, 0, stream>>>(Xp, Wp, Bp, Yp, SPb, ZPb, M, IC, OC, mode, NT, nsplit,
                                       4, 4, 4, 4, 4, 4, 4, 16, 16, 16, 1, 1, 1, 1, flags);
    if (nsplit > 1) {
      long MOC = (long)M * OC;
      k_combine<<<(int)((MOC + 255) / 256), 256, 0, stream>>>(SPb, Bp, Yp, MOC, ilg(OC),
                                                              nsplit, flags);
    }
  };

  k_tin<<<dim3(128, 4, 4), 256, 0, stream>>>(x, X0);

  // ---- TLG branch ----
  k_ln_f2b<<<4096, 256, 0, stream>>>(X0, n1_w, n1_b, XN, 16384);
  conv_gl(XN, tq2, tq_b, Qb, 16384, 128, 128, 0, 3, 3, 4);
  conv_gl(XN, tk2, tk_b, Kb, 16384, 128, 128, 0, 3, 3, 4);
  conv_gl(XN, tv2, tv_b, Vb, 16384, 128, 128, 0, 3, 3, 4);
  k_tlg_attn<<<4096, 256, 0, stream>>>(Qb, Kb, Vb, Yb);
  conv_gl(Yb, tp2, tp_b, X0, 16384, 128, 128, 0, 3, 3, 1);

  // ---- SLG branch ----
  k_ln_f2b<<<4096, 256, 0, stream>>>(X0, n2_w, n2_b, XN, 16384);
  conv_gl(XN, sq2, sq_b, Qb, 16384, 128, 128, 1, 27, 7, 4);
  conv(XN, sc2, sc_b, XC, 8,    128, 128, 1, 27, 2, 2, 2,   4, 16, 16, 16, 4, 8, 8, 8, 4);
  conv(XN, sf2, sf_b, XF, 1024, 128, 128, 1, 27, 8, 8, 8,   4, 16, 16, 16, 2, 2, 2, 2, 4);
  conv(XC, sk2, sk_b, Kf,            8,    128, 128, 1, 27, 2, 2, 2, 1, 2, 2, 2, 1, 1, 1, 1, 0);
  conv(XF, sk2, sk_b, Kf + 8 * 128,  1024, 128, 128, 1, 27, 8, 8, 8, 2, 8, 8, 8, 1, 1, 1, 1, 0);
  conv(XC, sv2, sv_b, Vf,            8,    128, 128, 1, 27, 2, 2, 2, 1, 2, 2, 2, 1, 1, 1, 1, 0);
  conv(XF, sv2, sv_b, Vf + 8 * 128,  1024, 128, 128, 1, 27, 8, 8, 8, 2, 8, 8, 8, 1, 1, 1, 1, 0);
  k_ln_f2b<<<258, 256, 0, stream>>>(Kf, sn_w, sn_b, Kb, 1032);
  k_ln_f2b<<<258, 256, 0, stream>>>(Vf, sn_w, sn_b, Vb, 1032);
  k_pack_kh<<<516, 256, 0, stream>>>(Kb, Kh);
  k_pack_vt<<<516, 256, 0, stream>>>(Vb, Vt);
  k_slg_flash<<<2048, 256, 0, stream>>>(Qb, Kh, Vt, Yb);
  conv_gl(Yb, sp2, sp_b, X0, 16384, 128, 128, 1, 27, 7, 1);

  // ---- MLP branch ----
  k_ln_f2b<<<4096, 256, 0, stream>>>(X0, n3_w, n3_b, XN, 16384);
  conv_gl256(XN, m12, m1_b, H, 16384, 128, 512, 2, 81, 2, 6);
  conv_gl(H, m22, m2_b, X0, 16384, 512, 128, 2, 81, 8, 1);

  k_tout<<<dim3(128, 4, 4), 256, 0, stream>>>(X0, (float*)d_out);
}

// Round 2
// 1208.839 us; speedup vs baseline: 1.0151x; 1.0151x over previous
//
#include <hip/hip_runtime.h>

typedef unsigned short u16;
typedef __attribute__((ext_vector_type(8))) short bf16x8;
typedef __attribute__((ext_vector_type(4))) float f32x4;

#define PITCH 40   // small-conv kernel LDS pitch (shorts)

__device__ __forceinline__ u16 f2bf(float f) {
  union { float f; unsigned u; } v; v.f = f;
  unsigned r = v.u + 0x7fffu + ((v.u >> 16) & 1u);
  return (u16)(r >> 16);
}
__device__ __forceinline__ float bf2f(u16 h) {
  union { unsigned u; float f; } v; v.u = ((unsigned)h) << 16;
  return v.f;
}
__device__ __forceinline__ float4 load4bf(const u16* p) {
  ushort4 h = *(const ushort4*)p;
  return make_float4(bf2f(h.x), bf2f(h.y), bf2f(h.z), bf2f(h.w));
}
// async global->LDS, 16B per lane; LDS dest = wave-uniform base + lane*16
__device__ __forceinline__ void gll16(const u16* g, u16* l) {
  __builtin_amdgcn_global_load_lds(
      (const __attribute__((address_space(1))) unsigned int*)g,
      (__attribute__((address_space(3))) unsigned int*)l, 16, 0, 0);
}

// ---------------- tiled transpose (l,c,s) -> token-major [(l,s), c] fp32 ----------------
__global__ __launch_bounds__(256) void k_tin(const float* __restrict__ x,
                                             float* __restrict__ xt) {
  __shared__ float t[32][33];
  int s0 = blockIdx.x * 32, c0 = blockIdx.y * 32, l = blockIdx.z;
  int r = threadIdx.x >> 3, q4 = (threadIdx.x & 7) * 4;
  float4 v = *(const float4*)(x + ((long)(l * 128 + c0 + r) << 12) + s0 + q4);
  t[r][q4] = v.x; t[r][q4 + 1] = v.y; t[r][q4 + 2] = v.z; t[r][q4 + 3] = v.w;
  __syncthreads();
  float4 o = {t[q4][r], t[q4 + 1][r], t[q4 + 2][r], t[q4 + 3][r]};
  *(float4*)(xt + ((long)(l * 4096 + s0 + r) << 7) + c0 + q4) = o;
}

__global__ __launch_bounds__(256) void k_tout(const float* __restrict__ xt,
                                              float* __restrict__ out) {
  __shared__ float t[32][33];
  int s0 = blockIdx.x * 32, c0 = blockIdx.y * 32, l = blockIdx.z;
  int r = threadIdx.x >> 3, q4 = (threadIdx.x & 7) * 4;
  float4 v = *(const float4*)(xt + ((long)(l * 4096 + s0 + r) << 7) + c0 + q4);
  t[r][q4] = v.x; t[r][q4 + 1] = v.y; t[r][q4 + 2] = v.z; t[r][q4 + 3] = v.w;
  __syncthreads();
  float4 o = {t[q4][r], t[q4 + 1][r], t[q4 + 2][r], t[q4 + 3][r]};
  *(float4*)(out + ((long)(l * 128 + c0 + r) << 12) + s0 + q4) = o;
}

__global__ __launch_bounds__(256) void k_zeropage(u16* __restrict__ zp) {
  zp[threadIdx.x] = 0; zp[threadIdx.x + 256] = 0;
  zp[threadIdx.x + 512] = 0; zp[threadIdx.x + 768] = 0;
}

// ---------------- layernorm fp32 in -> bf16 out, one wave per row ----------------
__global__ __launch_bounds__(256) void k_ln_f2b(const float* __restrict__ X,
                                                const float* __restrict__ g,
                                                const float* __restrict__ b,
                                                u16* __restrict__ Y, int M) {
  int n = blockIdx.x * 4 + (threadIdx.x >> 6);
  if (n >= M) return;
  int lane = threadIdx.x & 63;
  const float* row = X + (long)n * 128;
  float2 v = *(const float2*)(row + lane * 2);
  float s = v.x + v.y;
#pragma unroll
  for (int o = 32; o > 0; o >>= 1) s += __shfl_xor(s, o);
  float mu = s * (1.0f / 128.0f);
  float dx = v.x - mu, dy = v.y - mu;
  float q = dx * dx + dy * dy;
#pragma unroll
  for (int o = 32; o > 0; o >>= 1) q += __shfl_xor(q, o);
  float rs = rsqrtf(q * (1.0f / 128.0f) + 1e-5f);
  float2 gv = *(const float2*)(g + lane * 2);
  float2 bv = *(const float2*)(b + lane * 2);
  ushort2 o2;
  o2.x = f2bf(dx * rs * gv.x + bv.x);
  o2.y = f2bf(dy * rs * gv.y + bv.y);
  *(ushort2*)(Y + (long)n * 128 + lane * 2) = o2;
}

// ---------------- coalesced weight repack: W[oc][ic][t] fp32 -> Wb[t][oc][ic] bf16 ----------
__global__ __launch_bounds__(256) void k_repack2(const float* __restrict__ W,
                                                 u16* __restrict__ Wb,
                                                 int OC, int IC, int NT) {
  __shared__ float ws[128 * 81];
  int oc = blockIdx.x, ic0 = blockIdx.y * 128;
  const float* src = W + ((long)oc * IC + ic0) * NT;
  int n = 128 * NT;
  for (int i = threadIdx.x; i < n; i += 256) ws[i] = src[i];
  __syncthreads();
  u16* dst = Wb + (long)oc * IC + ic0;
  long tstep = (long)OC * IC;
  for (int idx = threadIdx.x; idx < n; idx += 256) {
    int t = idx >> 7, i = idx & 127;
    dst[(long)t * tstep + i] = f2bf(ws[i * NT + t]);
  }
}

// ---------------- small conv-as-gather-GEMM (64 x 64 tile) for small M ----------------
__global__ __launch_bounds__(256) void k_conv_mfma(
    const u16* __restrict__ X, const u16* __restrict__ W3,
    const float* __restrict__ bias, void* __restrict__ Yv,
    int M, int IC, int OC, int mode, int NT,
    int lgWo, int lgHo, int lgDo,
    int lgWi, int lgHi, int lgDi,
    int Li, int Di, int Hi, int Wi,
    int sL, int sD, int sH, int sW, int flags) {
  __shared__ u16 As[64 * PITCH];
  __shared__ u16 Bs[64 * PITCH];
  int tid = threadIdx.x;
  int wave = tid >> 6, lane = tid & 63;
  int quad = lane >> 4, l15 = lane & 15;
  int m0 = blockIdx.x * 64;
  int oc0 = blockIdx.y * 64;

  int srl = tid >> 2;
  int sao = (tid & 3) * 8;
  int sboc = tid >> 2, sbo = (tid & 3) * 8;

  int sm = m0 + srl;
  bool mv = sm < M;
  int w = sm & ((1 << lgWo) - 1);
  int h = (sm >> lgWo) & ((1 << lgHo) - 1);
  int d = (sm >> (lgWo + lgHo)) & ((1 << lgDo) - 1);
  int l = sm >> (lgWo + lgHo + lgDo);

  int c0 = 0, c1 = 0, c2 = 0, c3 = 0;
  auto comp_nb = [&]() -> long {
    if (!mv) return -1;
    int li, di, hi, wi; bool ok;
    if (mode == 0) {
      int dl = c0 - 1;
      int ll = (l & 1) + dl;
      ok = (ll >= 0 && ll < 2);
      li = l + dl; di = d; hi = h; wi = w;
    } else if (mode == 1) {
      li = l * sL; di = d * sD + c2 - 1; hi = h * sH + c1 - 1; wi = w * sW + c0 - 1;
      ok = ((unsigned)di < (unsigned)Di) && ((unsigned)hi < (unsigned)Hi) &&
           ((unsigned)wi < (unsigned)Wi);
    } else {
      li = l + c3 - 1; di = d + c2 - 1; hi = h + c1 - 1; wi = w + c0 - 1;
      ok = ((unsigned)li < (unsigned)Li) && ((unsigned)di < (unsigned)Di) &&
           ((unsigned)hi < (unsigned)Hi) && ((unsigned)wi < (unsigned)Wi);
    }
    if (!ok) return -1;
    return ((((long)((li << lgDi) + di) << lgHi) + hi) << lgWi) + wi;
  };

  long nb = comp_nb();
  const u16* wt = W3 + (long)(oc0 + sboc) * IC + sbo;
  long wstep = (long)OC * IC;
  int kmask = (IC >> 5) - 1;
  int total = NT * (IC >> 5);

  const bf16x8 Z = {0, 0, 0, 0, 0, 0, 0, 0};
  bf16x8 ra0 = Z, rb;
  if (nb >= 0) ra0 = *(const bf16x8*)(X + nb * IC + sao);
  rb = *(const bf16x8*)wt;

  f32x4 acc[4];
#pragma unroll
  for (int j = 0; j < 4; ++j) acc[j] = {0.f, 0.f, 0.f, 0.f};

  int wrow = wave * 16;

  for (int ks = 0; ks < total; ++ks) {
    __syncthreads();
    *(bf16x8*)&As[srl * PITCH + sao] = ra0;
    *(bf16x8*)&Bs[sboc * PITCH + sbo] = rb;
    __syncthreads();
    int ksn = ks + 1;
    if (ksn < total) {
      int k0n = (ksn & kmask) << 5;
      if ((ksn & kmask) == 0) {
        wt += wstep;
        if (++c0 == 3) { c0 = 0; if (++c1 == 3) { c1 = 0; if (++c2 == 3) { c2 = 0; ++c3; } } }
        nb = comp_nb();
      }
      ra0 = Z;
      if (nb >= 0) ra0 = *(const bf16x8*)(X + nb * IC + k0n + sao);
      rb = *(const bf16x8*)(wt + k0n);
    }
    bf16x8 a0 = *(const bf16x8*)&As[(wrow + l15) * PITCH + quad * 8];
#pragma unroll
    for (int j = 0; j < 4; ++j) {
      bf16x8 b = *(const bf16x8*)&Bs[(j * 16 + l15) * PITCH + quad * 8];
      acc[j] = __builtin_amdgcn_mfma_f32_16x16x32_bf16(a0, b, acc[j], 0, 0, 0);
    }
  }

  int col = oc0 + l15;
#pragma unroll
  for (int j = 0; j < 4; ++j) {
    float bj = bias[col + j * 16];
    int rbase = m0 + wrow + quad * 4;
#pragma unroll
    for (int r = 0; r < 4; ++r) {
      int row = rbase + r;
      if (row >= M) continue;
      float v = acc[j][r] + bj;
      if (flags & 2) v = fmaxf(v, 0.f);
      long off = (long)row * OC + col + j * 16;
      if (flags & 4) ((u16*)Yv)[off] = f2bf(v);
      else if (flags & 1) ((float*)Yv)[off] += v;
      else ((float*)Yv)[off] = v;
    }
  }
}

// ---------------- big conv-GEMM: 128x128 tile, BK=64, single-buffer global_load_lds ----------
__global__ __launch_bounds__(256, 4) void k_conv_gl(
    const u16* __restrict__ X, const u16* __restrict__ W3,
    const float* __restrict__ bias, void* __restrict__ Yv, float* __restrict__ SP,
    const u16* __restrict__ ZP,
    int M, int IC, int OC, int mode, int NT, int NSPLIT,
    int lgWo, int lgHo, int lgDo,
    int lgWi, int lgHi, int lgDi,
    int Li, int Di, int Hi, int Wi,
    int sL, int sD, int sH, int sW, int flags) {
  __shared__ __align__(16) u16 As[128 * 64];
  __shared__ __align__(16) u16 Bs[128 * 64];
  int tid = threadIdx.x;
  int wave = tid >> 6, lane = tid & 63;
  int quad = lane >> 4, l15 = lane & 15;
  int m0 = blockIdx.x * 128, oc0 = blockIdx.y * 128;
  int mi = wave & 1, ni = wave >> 1;

  int rp[4], cA[4], sm[4];
#pragma unroll
  for (int q = 0; q < 4; ++q) {
    rp[q] = wave * 32 + q * 8 + (lane >> 3);
    cA[q] = ((lane & 7) - (rp[q] >> 1)) & 7;
    sm[q] = m0 + rp[q];
  }

  int tap_per = (NT + NSPLIT - 1) / NSPLIT;
  int t0 = blockIdx.z * tap_per;
  int t1 = min(NT, t0 + tap_per);
  int kc = IC >> 6;
  int total = (t1 - t0) * kc;

  int c0 = t0 % 3, c1 = (t0 / 3) % 3, c2 = (t0 / 9) % 3, c3 = t0 / 27;
  auto comp_nb = [&](int smv) -> int {
    if (smv >= M) return -1;
    int w = smv & ((1 << lgWo) - 1);
    int h = (smv >> lgWo) & ((1 << lgHo) - 1);
    int d = (smv >> (lgWo + lgHo)) & ((1 << lgDo) - 1);
    int l = smv >> (lgWo + lgHo + lgDo);
    int li, di, hi, wi; bool ok;
    if (mode == 0) {
      int dl = c0 - 1;
      int ll = (l & 1) + dl;
      ok = (ll >= 0 && ll < 2);
      li = l + dl; di = d; hi = h; wi = w;
    } else if (mode == 1) {
      li = l * sL; di = d * sD + c2 - 1; hi = h * sH + c1 - 1; wi = w * sW + c0 - 1;
      ok = ((unsigned)di < (unsigned)Di) && ((unsigned)hi < (unsigned)Hi) &&
           ((unsigned)wi < (unsigned)Wi);
    } else {
      li = l + c3 - 1; di = d + c2 - 1; hi = h + c1 - 1; wi = w + c0 - 1;
      ok = ((unsigned)li < (unsigned)Li) && ((unsigned)di < (unsigned)Di) &&
           ((unsigned)hi < (unsigned)Hi) && ((unsigned)wi < (unsigned)Wi);
    }
    if (!ok) return -1;
    return (((li << lgDi) + di) << lgHi | hi) << lgWi | wi;
  };

  int nb[4];
#pragma unroll
  for (int q = 0; q < 4; ++q) nb[q] = comp_nb(sm[q]);
  long wstep = (long)OC * IC;
  const u16* wbase = W3 + (long)t0 * wstep + (long)oc0 * IC;

  f32x4 acc[4][4];
#pragma unroll
  for (int i = 0; i < 4; ++i)
#pragma unroll
    for (int j = 0; j < 4; ++j) acc[i][j] = {0.f, 0.f, 0.f, 0.f};

  int kk = 0;
  for (int ks = 0; ks < total; ++ks) {
    if (kk == kc) {
      kk = 0;
      if (++c0 == 3) { c0 = 0; if (++c1 == 3) { c1 = 0; if (++c2 == 3) { c2 = 0; ++c3; } } }
#pragma unroll
      for (int q = 0; q < 4; ++q) nb[q] = comp_nb(sm[q]);
      wbase += wstep;
    }
    int k0 = kk << 6;
    ++kk;
    __syncthreads();
#pragma unroll
    for (int q = 0; q < 4; ++q) {
      const u16* a = (nb[q] >= 0) ? X + (long)nb[q] * IC + k0 + cA[q] * 8 : ZP;
      gll16(a, &As[(wave * 4 + q) * 512]);
    }
#pragma unroll
    for (int q = 0; q < 4; ++q) {
      const u16* bsrc = wbase + (long)rp[q] * IC + k0 + cA[q] * 8;
      gll16(bsrc, &Bs[(wave * 4 + q) * 512]);
    }
    __syncthreads();
#pragma unroll
    for (int ksub = 0; ksub < 2; ++ksub) {
      bf16x8 af[4], bf[4];
#pragma unroll
      for (int i = 0; i < 4; ++i) {
        int row = mi * 64 + i * 16 + l15;
        int pa = ((ksub * 4 + quad) + (row >> 1)) & 7;
        af[i] = *(const bf16x8*)&As[row * 64 + pa * 8];
      }
#pragma unroll
      for (int j = 0; j < 4; ++j) {
        int row = ni * 64 + j * 16 + l15;
        int pb = ((ksub * 4 + quad) + (row >> 1)) & 7;
        bf[j] = *(const bf16x8*)&Bs[row * 64 + pb * 8];
      }
#pragma unroll
      for (int i = 0; i < 4; ++i)
#pragma unroll
        for (int j = 0; j < 4; ++j)
          acc[i][j] = __builtin_amdgcn_mfma_f32_16x16x32_bf16(af[i], bf[j], acc[i][j], 0, 0, 0);
    }
  }

  if (NSPLIT > 1) {
    float* out = SP + (long)blockIdx.z * M * OC;
#pragma unroll
    for (int j = 0; j < 4; ++j) {
      int c = oc0 + ni * 64 + j * 16 + l15;
#pragma unroll
      for (int i = 0; i < 4; ++i) {
        int rbase = m0 + mi * 64 + i * 16 + quad * 4;
#pragma unroll
        for (int r = 0; r < 4; ++r) {
          int row = rbase + r;
          if (row < M) out[(long)row * OC + c] = acc[i][j][r];
        }
      }
    }
  } else {
#pragma unroll
    for (int j = 0; j < 4; ++j) {
      int c = oc0 + ni * 64 + j * 16 + l15;
      float bj = bias[c];
#pragma unroll
      for (int i = 0; i < 4; ++i) {
        int rbase = m0 + mi * 64 + i * 16 + quad * 4;
#pragma unroll
        for (int r = 0; r < 4; ++r) {
          int row = rbase + r;
          if (row >= M) continue;
          float v = acc[i][j][r] + bj;
          if (flags & 2) v = fmaxf(v, 0.f);
          long off = (long)row * OC + c;
          if (flags & 4) ((u16*)Yv)[off] = f2bf(v);
          else if (flags & 1) ((float*)Yv)[off] += v;
          else ((float*)Yv)[off] = v;
        }
      }
    }
  }
}

// ---------------- 256x256 8-phase conv-GEMM (T2+T3+T4+T5), BK=64, 8 waves ----------------
// Round-2 fixes vs round-1: (a) schedule pinned per rule #18 (sched_barrier(0) +
// explicit lgkmcnt(0) asm after raw s_barrier) so ds_reads issue BEFORE the barrier
// and their latency hides under barrier arrival; (b) all per-phase address VALU
// hoisted: LDS read offsets collapse to 2 scalars + compile-time immediates (swizzle
// chunk invariant under row+16/+64), staging uses rolling pointers (stage index
// s=2*kt+ks advances by exactly 1 per call; gather recompute only on tap change).
// vmcnt(8) twice per K-tile, never 0 in loop. Regions: [buf*2+ks] of 256rows x 32shorts.
__global__ __launch_bounds__(512, 2) void k_conv_g256(
    const u16* __restrict__ X, const u16* __restrict__ W3,
    const float* __restrict__ bias, void* __restrict__ Yv, float* __restrict__ SP,
    const u16* __restrict__ ZP,
    int M, int IC, int OC, int mode, int NT, int NSPLIT,
    int lgWo, int lgHo, int lgDo,
    int lgWi, int lgHi, int lgDi,
    int Li, int Di, int Hi, int Wi,
    int sL, int sD, int sH, int sW, int flags) {
  __shared__ __align__(16) u16 Ab[4][8192];   // 64 KiB, region = buf*2+ks
  __shared__ __align__(16) u16 Bb[4][8192];   // 64 KiB
  int tid = threadIdx.x;
  int wave = tid >> 6, lane = tid & 63;
  int quad = lane >> 4, l15 = lane & 15;
  int wr = wave >> 2, wc = wave & 3;
  int m0 = blockIdx.x * 256, oc0 = blockIdx.y * 256;

  // staging geometry: thread covers rows srow0 and srow0+128, 16B phys chunk spc
  int srow0 = tid >> 2;
  int spc = tid & 3;
  int lc0 = (spc - (srow0 >> 1)) & 3;          // logical k-chunk at this slot
  int lc1 = (spc - ((srow0 + 128) >> 1)) & 3;

  int kc = IC >> 6;
  int hsPerTap = kc << 1;
  int tap_per = (NT + NSPLIT - 1) / NSPLIT;
  int t0 = blockIdx.z * tap_per;
  int t1 = min(NT, t0 + tap_per);
  int TOT = (t1 - t0) * kc;
  int TOTH = TOT * 2;

  int c0 = t0 % 3, c1 = (t0 / 3) % 3, c2 = (t0 / 9) % 3, c3 = t0 / 27;
  auto comp_nb = [&](int smv) -> int {
    if (smv >= M) return -1;
    int w = smv & ((1 << lgWo) - 1);
    int h = (smv >> lgWo) & ((1 << lgHo) - 1);
    int d = (smv >> (lgWo + lgHo)) & ((1 << lgDo) - 1);
    int l = smv >> (lgWo + lgHo + lgDo);
    int li, di, hi, wi; bool ok;
    if (mode == 0) {
      int dl = c0 - 1;
      int ll = (l & 1) + dl;
      ok = (ll >= 0 && ll < 2);
      li = l + dl; di = d; hi = h; wi = w;
    } else if (mode == 1) {
      li = l * sL; di = d * sD + c2 - 1; hi = h * sH + c1 - 1; wi = w * sW + c0 - 1;
      ok = ((unsigned)di < (unsigned)Di) && ((unsigned)hi < (unsigned)Hi) &&
           ((unsigned)wi < (unsigned)Wi);
    } else {
      li = l + c3 - 1; di = d + c2 - 1; hi = h + c1 - 1; wi = w + c0 - 1;
      ok = ((unsigned)li < (unsigned)Li) && ((unsigned)di < (unsigned)Di) &&
           ((unsigned)hi < (unsigned)Hi) && ((unsigned)wi < (unsigned)Wi);
    }
    if (!ok) return -1;
    return (((li << lgDi) + di) << lgHi | hi) << lgWi | wi;
  };

  // ---- A staging state (gather; recompute on tap change only) ----
  int nb0 = comp_nb(m0 + srow0);
  int nb1 = comp_nb(m0 + srow0 + 128);
  const u16* ap0;
  const u16* ap1;
  auto setAp = [&]() {
    ap0 = (nb0 >= 0) ? X + (long)nb0 * IC + lc0 * 8 : ZP;
    ap1 = (nb1 >= 0) ? X + (long)nb1 * IC + lc1 * 8 : ZP;
  };
  setAp();
  int ahs = 0, sA = 0;
  u16* adst = &Ab[0][wave << 9];
  auto stageA = [&]() {
    u16* d = adst + ((sA & 3) << 13);
    ++sA;
    if (sA > TOTH) { gll16(ZP, d); gll16(ZP, d + 4096); return; }
    gll16(ap0 + (ahs << 5), d);
    gll16(ap1 + (ahs << 5), d + 4096);
    if (++ahs == hsPerTap) {
      ahs = 0;
      if (++c0 == 3) { c0 = 0; if (++c1 == 3) { c1 = 0; if (++c2 == 3) { c2 = 0; ++c3; } } }
      nb0 = comp_nb(m0 + srow0);
      nb1 = comp_nb(m0 + srow0 + 128);
      setAp();
    }
  };

  // ---- B staging state (rolling pointer) ----
  long wstep = (long)OC * IC;
  const u16* bp = W3 + ((long)t0 * OC + oc0 + srow0) * IC + lc0 * 8;
  long bdlt = (long)128 * IC + (lc1 - lc0) * 8;
  long btap = wstep - (long)(hsPerTap - 1) * 32;
  int bhs = 0, sB = 0;
  u16* bdst = &Bb[0][wave << 9];
  auto stageB = [&]() {
    u16* d = bdst + ((sB & 3) << 13);
    ++sB;
    if (sB > TOTH) { gll16(ZP, d); gll16(ZP, d + 4096); return; }
    gll16(bp, d);
    gll16(bp + bdlt, d + 4096);
    if (++bhs == hsPerTap) { bhs = 0; bp += btap; }
    else bp += 32;
  };

  // ---- precomputed LDS read bases (swizzle chunk invariant under row+16/+64) ----
  int rowA0 = (wr << 7) + l15;
  int rA0 = rowA0 * 32 + (((quad + (rowA0 >> 1)) & 3) << 3);
  int rowB0 = (wc << 6) + l15;
  int rB0 = rowB0 * 32 + (((quad + (rowB0 >> 1)) & 3) << 3);
  const u16* Abase = &Ab[0][0];
  const u16* Bbase = &Bb[0][0];

  f32x4 acc[8][4];
#pragma unroll
  for (int i = 0; i < 8; ++i)
#pragma unroll
    for (int j = 0; j < 4; ++j) acc[i][j] = {0.f, 0.f, 0.f, 0.f};

  bf16x8 af[4], bfr[4];
  auto rdA = [&](int reg, int ih) {
    const u16* pA = Abase + (reg << 13) + (ih << 11) + rA0;
#pragma unroll
    for (int i = 0; i < 4; ++i) af[i] = *(const bf16x8*)(pA + (i << 9));
  };
  auto rdB = [&](int reg) {
    const u16* pB = Bbase + (reg << 13) + rB0;
#pragma unroll
    for (int j = 0; j < 4; ++j) bfr[j] = *(const bf16x8*)(pB + (j << 9));
  };
  auto mf = [&](int ih) {
    __builtin_amdgcn_s_setprio(1);
#pragma unroll
    for (int i = 0; i < 4; ++i)
#pragma unroll
      for (int j = 0; j < 4; ++j)
        acc[(ih << 2) + i][j] =
            __builtin_amdgcn_mfma_f32_16x16x32_bf16(af[i], bfr[j], acc[(ih << 2) + i][j], 0, 0, 0);
    __builtin_amdgcn_s_setprio(0);
  };

  // prologue: stage s=0..2 for A and B (interleaved A,B,A,B,A,B = 12 loads);
  // vmcnt(8) completes the 4 oldest = A(0,0),B(0,0)
  stageA(); stageB();
  stageA(); stageB();
  stageA(); stageB();
  asm volatile("s_waitcnt vmcnt(8)" ::: "memory");
  __builtin_amdgcn_s_barrier();

  for (int n = 0; n < TOT; ++n) {
    int rg = (n & 1) << 1;
    // ---- phase 0: ks=0, i-half 0 ----
    rdA(rg, 0); rdB(rg);
    stageA();                                   // (n+1, ks=1)
    __builtin_amdgcn_sched_barrier(0);
    __builtin_amdgcn_s_barrier();
    asm volatile("s_waitcnt lgkmcnt(0)" ::: "memory");
    __builtin_amdgcn_sched_barrier(0);
    mf(0);
    __builtin_amdgcn_sched_barrier(0);
    __builtin_amdgcn_s_barrier();
    // ---- phase 1: ks=0, i-half 1 (B reused in regs) ----
    rdA(rg, 1);
    stageB();                                   // (n+1, ks=1)
    __builtin_amdgcn_sched_barrier(0);
    __builtin_amdgcn_s_barrier();
    asm volatile("s_waitcnt lgkmcnt(0)" ::: "memory");
    __builtin_amdgcn_sched_barrier(0);
    mf(1);
    __builtin_amdgcn_sched_barrier(0);
    asm volatile("s_waitcnt vmcnt(8)" ::: "memory");
    __builtin_amdgcn_s_barrier();
    // ---- phase 2: ks=1, i-half 0 ----
    rdA(rg + 1, 0); rdB(rg + 1);
    stageA();                                   // (n+2, ks=0)
    __builtin_amdgcn_sched_barrier(0);
    __builtin_amdgcn_s_barrier();
    asm volatile("s_waitcnt lgkmcnt(0)" ::: "memory");
    __builtin_amdgcn_sched_barrier(0);
    mf(0);
    __builtin_amdgcn_sched_barrier(0);
    __builtin_amdgcn_s_barrier();
    // ---- phase 3: ks=1, i-half 1 ----
    rdA(rg + 1, 1);
    stageB();                                   // (n+2, ks=0)
    __builtin_amdgcn_sched_barrier(0);
    __builtin_amdgcn_s_barrier();
    asm volatile("s_waitcnt lgkmcnt(0)" ::: "memory");
    __builtin_amdgcn_sched_barrier(0);
    mf(1);
    __builtin_amdgcn_sched_barrier(0);
    asm volatile("s_waitcnt vmcnt(8)" ::: "memory");
    __builtin_amdgcn_s_barrier();
  }

  // epilogue: C/D layout col=l15, row=quad*4+r
  if (NSPLIT > 1) {
    float* outp = SP + (long)blockIdx.z * M * OC;
#pragma unroll
    for (int i = 0; i < 8; ++i)
#pragma unroll
      for (int j = 0; j < 4; ++j) {
        int c = oc0 + (wc << 6) + (j << 4) + l15;
        int rb = m0 + (wr << 7) + (i << 4) + (quad << 2);
#pragma unroll
        for (int r = 0; r < 4; ++r) {
          int row = rb + r;
          if (row < M) outp[(long)row * OC + c] = acc[i][j][r];
        }
      }
  } else {
#pragma unroll
    for (int i = 0; i < 8; ++i)
#pragma unroll
      for (int j = 0; j < 4; ++j) {
        int c = oc0 + (wc << 6) + (j << 4) + l15;
        float bj = bias[c];
        int rb = m0 + (wr << 7) + (i << 4) + (quad << 2);
#pragma unroll
        for (int r = 0; r < 4; ++r) {
          int row = rb + r;
          if (row >= M) continue;
          float v = acc[i][j][r] + bj;
          if (flags & 2) v = fmaxf(v, 0.f);
          long off = (long)row * OC + c;
          if (flags & 4) ((u16*)Yv)[off] = f2bf(v);
          else if (flags & 1) ((float*)Yv)[off] += v;
          else ((float*)Yv)[off] = v;
        }
      }
  }
}

// ---------------- combine split-K partials: out = (sum_s SP[s]) + bias ----------------
__global__ __launch_bounds__(256) void k_combine(const float* __restrict__ SP,
                                                 const float* __restrict__ bias,
                                                 void* __restrict__ out,
                                                 long MOC, int lgOC, int nsplit, int flags) {
  long idx = (long)blockIdx.x * 256 + threadIdx.x;
  if (idx >= MOC) return;
  float v = bias[idx & ((1 << lgOC) - 1)];
  for (int s = 0; s < nsplit; ++s) v += SP[s * MOC + idx];
  if (flags & 2) v = fmaxf(v, 0.f);
  if (flags & 4) ((u16*)out)[idx] = f2bf(v);
  else if (flags & 1) ((float*)out)[idx] += v;
  else ((float*)out)[idx] = v;
}

// ---------------- TLG windowed cross attention: 8q x 8k per (window, head), bf16 ----------------
__global__ __launch_bounds__(256) void k_tlg_attn(const u16* __restrict__ Q,
                                                  const u16* __restrict__ K,
                                                  const u16* __restrict__ V,
                                                  u16* __restrict__ Y) {
  int gw = blockIdx.x * 4 + (threadIdx.x >> 6);
  int lane = threadIdx.x & 63;
  int head = gw & 7;
  int win = gw >> 3;
  int wB = win & 7, hB = (win >> 3) & 7, dB = (win >> 6) & 7, l = win >> 9;
  int i = lane >> 3, j = lane & 7;
  int nq = (l << 12) | ((dB * 2 + (i >> 2)) << 8) | ((hB * 2 + ((i >> 1) & 1)) << 4) |
           (wB * 2 + (i & 1));
  int lk = l ^ 2;
  int nk = (lk << 12) | ((dB * 2 + (j >> 2)) << 8) | ((hB * 2 + ((j >> 1) & 1)) << 4) |
           (wB * 2 + (j & 1));
  int hoff = head * 16;
  const u16* qp = Q + (long)nq * 128 + hoff;
  const u16* kp = K + (long)nk * 128 + hoff;
  float s = 0.f;
#pragma unroll
  for (int t = 0; t < 16; t += 4) {
    float4 a = load4bf(qp + t);
    float4 b = load4bf(kp + t);
    s += a.x * b.x + a.y * b.y + a.z * b.z + a.w * b.w;
  }
  s *= 0.25f;
  float mx = s;
#pragma unroll
  for (int o = 1; o < 8; o <<= 1) mx = fmaxf(mx, __shfl_xor(mx, o));
  float e = __expf(s - mx);
  float sum = e;
#pragma unroll
  for (int o = 1; o < 8; o <<= 1) sum += __shfl_xor(sum, o);
  float p = e / sum;
  const u16* vp = V + (long)nk * 128 + hoff;
  float y[16];
#pragma unroll
  for (int t = 0; t < 16; t += 4) {
    float4 vv = load4bf(vp + t);
    y[t] = p * vv.x; y[t + 1] = p * vv.y; y[t + 2] = p * vv.z; y[t + 3] = p * vv.w;
  }
#pragma unroll
  for (int o = 1; o < 8; o <<= 1) {
#pragma unroll
    for (int t = 0; t < 16; ++t) y[t] += __shfl_xor(y[t], o);
  }
  if (j == 0) {
    u16* yp = Y + (long)nq * 128 + hoff;
    u16 tmp[16];
#pragma unroll
    for (int t = 0; t < 16; ++t) tmp[t] = f2bf(y[t]);
    *(uint4*)(yp) = *(uint4*)tmp;
    *(uint4*)(yp + 8) = *(uint4*)(tmp + 8);
  }
}

// ---------------- SLG K/V repack for flash attn ----------------
__global__ __launch_bounds__(256) void k_pack_kh(const u16* __restrict__ Kin,
                                                 u16* __restrict__ Kh) {
  int idx = blockIdx.x * 256 + threadIdx.x;
  if (idx >= 8 * 1032 * 16) return;
  int d = idx & 15;
  int r = idx >> 4;
  int k = r % 1032, h = r / 1032;
  Kh[idx] = Kin[k * 128 + h * 16 + d];
}
__global__ __launch_bounds__(256) void k_pack_vt(const u16* __restrict__ Vin,
                                                 u16* __restrict__ Vt) {
  int idx = blockIdx.x * 256 + threadIdx.x;
  if (idx >= 8 * 16 * 1032) return;
  int k = idx % 1032;
  int r = idx / 1032;
  int d = r & 15, h = r >> 4;
  Vt[idx] = Vin[k * 128 + h * 16 + d];
}

// ---------------- SLG MFMA flash attention ----------------
__global__ __launch_bounds__(256) void k_slg_flash(const u16* __restrict__ Q,
                                                   const u16* __restrict__ Kh,
                                                   const u16* __restrict__ Vt,
                                                   u16* __restrict__ Y) {
  constexpr int NK = 1032;
  constexpr int NTILE = 17;
  __shared__ __align__(16) u16 Ks[64 * 24];
  __shared__ __align__(16) u16 Vs[16 * 72];
  __shared__ __align__(16) u16 Ps[4][16 * 72];
  int tid = threadIdx.x;
  int wave = tid >> 6, lane = tid & 63;
  int quad = lane >> 4, l15 = lane & 15;
  int h = blockIdx.x & 7;
  int q0 = (blockIdx.x >> 3) * 64 + wave * 16;

  const bf16x8 Zb = {0, 0, 0, 0, 0, 0, 0, 0};
  bf16x8 qf = Zb;
  if (quad < 2) qf = *(const bf16x8*)(Q + (long)(q0 + l15) * 128 + h * 16 + quad * 8);

  const u16* Kbase = Kh + (long)h * NK * 16;
  const u16* Vbase = Vt + (long)h * 16 * NK;

  float mrow[4], lrow[4];
  f32x4 oacc = {0.f, 0.f, 0.f, 0.f};
#pragma unroll
  for (int r = 0; r < 4; ++r) { mrow[r] = -1e30f; lrow[r] = 0.f; }

  int skey = tid >> 2, sch = (tid & 3) * 4;
  int svd = tid >> 4, svc = (tid & 15) * 4;

  for (int t = 0; t < NTILE; ++t) {
    int k0 = t * 64;
    __syncthreads();
    {
      short4 v = {0, 0, 0, 0};
      int key = k0 + skey;
      if (key < NK) v = *(const short4*)(Kbase + key * 16 + sch);
      *(short4*)&Ks[skey * 24 + sch] = v;
    }
    {
      short4 v = {0, 0, 0, 0};
      int colb = k0 + svc;
      if (colb < NK) v = *(const short4*)(Vbase + svd * NK + colb);
      *(short4*)&Vs[svd * 72 + svc] = v;
    }
    __syncthreads();

    f32x4 s[4];
#pragma unroll
    for (int sub = 0; sub < 4; ++sub) {
      bf16x8 b = Zb;
      if (quad < 2) b = *(const bf16x8*)&Ks[(sub * 16 + l15) * 24 + quad * 8];
      f32x4 zero = {0.f, 0.f, 0.f, 0.f};
      s[sub] = __builtin_amdgcn_mfma_f32_16x16x32_bf16(qf, b, zero, 0, 0, 0);
    }
    float pv[4][4];
    float tmax[4] = {-1e30f, -1e30f, -1e30f, -1e30f};
#pragma unroll
    for (int sub = 0; sub < 4; ++sub) {
      int key = k0 + sub * 16 + l15;
      bool valid = key < NK;
#pragma unroll
      for (int r = 0; r < 4; ++r) {
        float sv = valid ? s[sub][r] * 0.25f : -1e30f;
        pv[sub][r] = sv;
        tmax[r] = fmaxf(tmax[r], sv);
      }
    }
#pragma unroll
    for (int o = 1; o < 16; o <<= 1)
#pragma unroll
      for (int r = 0; r < 4; ++r) tmax[r] = fmaxf(tmax[r], __shfl_xor(tmax[r], o));

    float al[4], tsum[4] = {0.f, 0.f, 0.f, 0.f};
#pragma unroll
    for (int r = 0; r < 4; ++r) {
      float mn = fmaxf(mrow[r], tmax[r]);
      al[r] = __expf(mrow[r] - mn);
      mrow[r] = mn;
    }
#pragma unroll
    for (int sub = 0; sub < 4; ++sub)
#pragma unroll
      for (int r = 0; r < 4; ++r) {
        float pe = __expf(pv[sub][r] - mrow[r]);
        tsum[r] += pe;
        Ps[wave][(quad * 4 + r) * 72 + sub * 16 + l15] = f2bf(pe);
      }
#pragma unroll
    for (int o = 1; o < 16; o <<= 1)
#pragma unroll
      for (int r = 0; r < 4; ++r) tsum[r] += __shfl_xor(tsum[r], o);
#pragma unroll
    for (int r = 0; r < 4; ++r) {
      lrow[r] = lrow[r] * al[r] + tsum[r];
      oacc[r] *= al[r];
    }
    bf16x8 pa0 = *(const bf16x8*)&Ps[wave][l15 * 72 + quad * 8];
    bf16x8 pa1 = *(const bf16x8*)&Ps[wave][l15 * 72 + 32 + quad * 8];
    bf16x8 vb0 = *(const bf16x8*)&Vs[l15 * 72 + quad * 8];
    bf16x8 vb1 = *(const bf16x8*)&Vs[l15 * 72 + 32 + quad * 8];
    oacc = __builtin_amdgcn_mfma_f32_16x16x32_bf16(pa0, vb0, oacc, 0, 0, 0);
    oacc = __builtin_amdgcn_mfma_f32_16x16x32_bf16(pa1, vb1, oacc, 0, 0, 0);
  }

#pragma unroll
  for (int r = 0; r < 4; ++r) {
    float inv = 1.0f / lrow[r];
    Y[(long)(q0 + quad * 4 + r) * 128 + h * 16 + l15] = f2bf(oacc[r] * inv);
  }
}

static inline int ilg(int v) { int r = 0; while ((1 << r) < v) ++r; return r; }

extern "C" void kernel_launch(void* const* d_in, const int* in_sizes, int n_in,
                              void* d_out, int out_size, void* d_ws, size_t ws_size,
                              hipStream_t stream) {
  (void)in_sizes; (void)n_in; (void)out_size; (void)ws_size;
  const float* x    = (const float*)d_in[0];
  const float* n1_w = (const float*)d_in[1];  const float* n1_b = (const float*)d_in[2];
  const float* n2_w = (const float*)d_in[3];  const float* n2_b = (const float*)d_in[4];
  const float* n3_w = (const float*)d_in[5];  const float* n3_b = (const float*)d_in[6];
  const float* sn_w = (const float*)d_in[7];  const float* sn_b = (const float*)d_in[8];
  const float* tq_w = (const float*)d_in[9];  const float* tq_b = (const float*)d_in[10];
  const float* tk_w = (const float*)d_in[11]; const float* tk_b = (const float*)d_in[12];
  const float* tv_w = (const float*)d_in[13]; const float* tv_b = (const float*)d_in[14];
  const float* tp_w = (const float*)d_in[15]; const float* tp_b = (const float*)d_in[16];
  const float* sq_w = (const float*)d_in[17]; const float* sq_b = (const float*)d_in[18];
  const float* sk_w = (const float*)d_in[19]; const float* sk_b = (const float*)d_in[20];
  const float* sv_w = (const float*)d_in[21]; const float* sv_b = (const float*)d_in[22];
  const float* sp_w = (const float*)d_in[23]; const float* sp_b = (const float*)d_in[24];
  const float* sf_w = (const float*)d_in[25]; const float* sf_b = (const float*)d_in[26];
  const float* sc_w = (const float*)d_in[27]; const float* sc_b = (const float*)d_in[28];
  const float* m1_w = (const float*)d_in[29]; const float* m1_b = (const float*)d_in[30];
  const float* m2_w = (const float*)d_in[31]; const float* m2_b = (const float*)d_in[32];

  char* p = (char*)d_ws;
  auto alloc = [&](size_t bytes) { char* r = p; p += (bytes + 255) & ~(size_t)255; return r; };
  const long N = 16384;
  float* X0 = (float*)alloc(N * 128 * 4);
  u16* XN = (u16*)alloc(N * 128 * 2);
  u16* Qb = (u16*)alloc(N * 128 * 2);
  u16* Kb = (u16*)alloc(N * 128 * 2);
  u16* Vb = (u16*)alloc(N * 128 * 2);
  u16* Yb = (u16*)alloc(N * 128 * 2);
  u16* H  = (u16*)alloc(N * 512 * 2);
  u16* XC = (u16*)alloc(8 * 128 * 2);
  u16* XF = (u16*)alloc(1024 * 128 * 2);
  float* Kf = (float*)alloc(1032 * 128 * 4);
  float* Vf = (float*)alloc(1032 * 128 * 4);
  u16* Kh = (u16*)alloc(8 * 1032 * 16 * 2);
  u16* Vt = (u16*)alloc(8 * 16 * 1032 * 2);
  float* SPb = (float*)alloc(2L * N * 512 * 4);  // split-K partials (64 MB)
  u16* ZPb = (u16*)alloc(2048);                   // zero page for masked gather rows
  u16* tq2 = (u16*)alloc(49152 * 2);  u16* tk2 = (u16*)alloc(49152 * 2);
  u16* tv2 = (u16*)alloc(49152 * 2);  u16* tp2 = (u16*)alloc(49152 * 2);
  u16* sq2 = (u16*)alloc(442368 * 2); u16* sk2 = (u16*)alloc(442368 * 2);
  u16* sv2 = (u16*)alloc(442368 * 2); u16* sp2 = (u16*)alloc(442368 * 2);
  u16* sf2 = (u16*)alloc(442368 * 2); u16* sc2 = (u16*)alloc(442368 * 2);
  u16* m12 = (u16*)alloc(5308416L * 2);
  u16* m22 = (u16*)alloc(5308416L * 2);

  k_zeropage<<<1, 256, 0, stream>>>(ZPb);

  auto rp = [&](const float* W, u16* Wb, int OC, int IC, int NT) {
    dim3 g(OC, IC / 128);
    k_repack2<<<g, 256, 0, stream>>>(W, Wb, OC, IC, NT);
  };
  rp(tq_w, tq2, 128, 128, 3);  rp(tk_w, tk2, 128, 128, 3);
  rp(tv_w, tv2, 128, 128, 3);  rp(tp_w, tp2, 128, 128, 3);
  rp(sq_w, sq2, 128, 128, 27); rp(sk_w, sk2, 128, 128, 27);
  rp(sv_w, sv2, 128, 128, 27); rp(sp_w, sp2, 128, 128, 27);
  rp(sf_w, sf2, 128, 128, 27); rp(sc_w, sc2, 128, 128, 27);
  rp(m1_w, m12, 512, 128, 81); rp(m2_w, m22, 128, 512, 81);

  auto conv = [&](const u16* Xp, const u16* Wp, const float* Bp, void* Yp,
                  int M, int IC, int OC, int mode, int NT,
                  int Do, int Ho, int Wo, int Li, int Di, int Hi, int Wi,
                  int sL, int sD, int sH, int sW, int flags) {
    int lgWo = ilg(Wo), lgHo = ilg(Ho), lgDo = ilg(Do);
    int lgWi = ilg(Wi), lgHi = ilg(Hi), lgDi = ilg(Di);
    dim3 g((M + 63) / 64, OC / 64);
    k_conv_mfma<<<g, 256, 0, stream>>>(Xp, Wp, Bp, Yp, M, IC, OC, mode, NT,
                                       lgWo, lgHo, lgDo, lgWi, lgHi, lgDi,
                                       Li, Di, Hi, Wi, sL, sD, sH, sW, flags);
  };
  auto conv_gl = [&](const u16* Xp, const u16* Wp, const float* Bp, void* Yp,
                     int M, int IC, int OC, int mode, int NT, int nsplit, int flags) {
    dim3 g(M / 128, OC / 128, nsplit);
    k_conv_gl<<<g, 256, 0, stream>>>(Xp, Wp, Bp, Yp, SPb, ZPb, M, IC, OC, mode, NT, nsplit,
                                     4, 4, 4, 4, 4, 4, 4, 16, 16, 16, 1, 1, 1, 1, flags);
    if (nsplit > 1) {
      long MOC = (long)M * OC;
      k_combine<<<(int)((MOC + 255) / 256), 256, 0, stream>>>(SPb, Bp, Yp, MOC, ilg(OC),
                                                              nsplit, flags);
    }
  };
  // 256x256 8-phase kernel (needs M%256==0 and OC%256==0)
  auto conv_gl256 = [&](const u16* Xp, const u16* Wp, const float* Bp, void* Yp,
                        int M, int IC, int OC, int mode, int NT, int nsplit, int flags) {
    dim3 g(M / 256, OC / 256, nsplit);
    k_conv_g256<<<g, 512, 0, stream>>>(Xp, Wp, Bp, Yp, SPb, ZPb, M, IC, OC, mode, NT, nsplit,
                                       4, 4, 4, 4, 4, 4, 4, 16, 16, 16, 1, 1, 1, 1, flags);
    if (nsplit > 1) {
      long MOC = (long)M * OC;
      k_combine<<<(int)((MOC + 255) / 256), 256, 0, stream>>>(SPb, Bp, Yp, MOC, ilg(OC),
                                                              nsplit, flags);
    }
  };

  k_tin<<<dim3(128, 4, 4), 256, 0, stream>>>(x, X0);

  // ---- TLG branch ----
  k_ln_f2b<<<4096, 256, 0, stream>>>(X0, n1_w, n1_b, XN, 16384);
  conv_gl(XN, tq2, tq_b, Qb, 16384, 128, 128, 0, 3, 3, 4);
  conv_gl(XN, tk2, tk_b, Kb, 16384, 128, 128, 0, 3, 3, 4);
  conv_gl(XN, tv2, tv_b, Vb, 16384, 128, 128, 0, 3, 3, 4);
  k_tlg_attn<<<4096, 256, 0, stream>>>(Qb, Kb, Vb, Yb);
  conv_gl(Yb, tp2, tp_b, X0, 16384, 128, 128, 0, 3, 3, 1);

  // ---- SLG branch ----
  k_ln_f2b<<<4096, 256, 0, stream>>>(X0, n2_w, n2_b, XN, 16384);
  conv_gl(XN, sq2, sq_b, Qb, 16384, 128, 128, 1, 27, 7, 4);
  conv(XN, sc2, sc_b, XC, 8,    128, 128, 1, 27, 2, 2, 2,   4, 16, 16, 16, 4, 8, 8, 8, 4);
  conv(XN, sf2, sf_b, XF, 1024, 128, 128, 1, 27, 8, 8, 8,   4, 16, 16, 16, 2, 2, 2, 2, 4);
  conv(XC, sk2, sk_b, Kf,            8,    128, 128, 1, 27, 2, 2, 2, 1, 2, 2, 2, 1, 1, 1, 1, 0);
  conv(XF, sk2, sk_b, Kf + 8 * 128,  1024, 128, 128, 1, 27, 8, 8, 8, 2, 8, 8, 8, 1, 1, 1, 1, 0);
  conv(XC, sv2, sv_b, Vf,            8,    128, 128, 1, 27, 2, 2, 2, 1, 2, 2, 2, 1, 1, 1, 1, 0);
  conv(XF, sv2, sv_b, Vf + 8 * 128,  1024, 128, 128, 1, 27, 8, 8, 8, 2, 8, 8, 8, 1, 1, 1, 1, 0);
  k_ln_f2b<<<258, 256, 0, stream>>>(Kf, sn_w, sn_b, Kb, 1032);
  k_ln_f2b<<<258, 256, 0, stream>>>(Vf, sn_w, sn_b, Vb, 1032);
  k_pack_kh<<<516, 256, 0, stream>>>(Kb, Kh);
  k_pack_vt<<<516, 256, 0, stream>>>(Vb, Vt);
  k_slg_flash<<<2048, 256, 0, stream>>>(Qb, Kh, Vt, Yb);
  conv_gl(Yb, sp2, sp_b, X0, 16384, 128, 128, 1, 27, 7, 1);

  // ---- MLP branch ----
  k_ln_f2b<<<4096, 256, 0, stream>>>(X0, n3_w, n3_b, XN, 16384);
  conv_gl256(XN, m12, m1_b, H, 16384, 128, 512, 2, 81, 2, 6);
  conv_gl(H, m22, m2_b, X0, 16384, 512, 128, 2, 81, 8, 1);

  k_tout<<<dim3(128, 4, 4), 256, 0, stream>>>(X0, (float*)d_out);
}

// Round 3
// 1202.227 us; speedup vs baseline: 1.0207x; 1.0055x over previous
//
#include <hip/hip_runtime.h>

typedef unsigned short u16;
typedef __attribute__((ext_vector_type(8))) short bf16x8;
typedef __attribute__((ext_vector_type(4))) float f32x4;

#define PITCH 40   // small-conv kernel LDS pitch (shorts)

__device__ __forceinline__ u16 f2bf(float f) {
  union { float f; unsigned u; } v; v.f = f;
  unsigned r = v.u + 0x7fffu + ((v.u >> 16) & 1u);
  return (u16)(r >> 16);
}
__device__ __forceinline__ float bf2f(u16 h) {
  union { unsigned u; float f; } v; v.u = ((unsigned)h) << 16;
  return v.f;
}
__device__ __forceinline__ float4 load4bf(const u16* p) {
  ushort4 h = *(const ushort4*)p;
  return make_float4(bf2f(h.x), bf2f(h.y), bf2f(h.z), bf2f(h.w));
}
// async global->LDS, 16B per lane; LDS dest = wave-uniform base + lane*16
__device__ __forceinline__ void gll16(const u16* g, u16* l) {
  __builtin_amdgcn_global_load_lds(
      (const __attribute__((address_space(1))) unsigned int*)g,
      (__attribute__((address_space(3))) unsigned int*)l, 16, 0, 0);
}

// ---------------- tiled transpose (l,c,s) -> token-major [(l,s), c] fp32 ----------------
__global__ __launch_bounds__(256) void k_tin(const float* __restrict__ x,
                                             float* __restrict__ xt) {
  __shared__ float t[32][33];
  int s0 = blockIdx.x * 32, c0 = blockIdx.y * 32, l = blockIdx.z;
  int r = threadIdx.x >> 3, q4 = (threadIdx.x & 7) * 4;
  float4 v = *(const float4*)(x + ((long)(l * 128 + c0 + r) << 12) + s0 + q4);
  t[r][q4] = v.x; t[r][q4 + 1] = v.y; t[r][q4 + 2] = v.z; t[r][q4 + 3] = v.w;
  __syncthreads();
  float4 o = {t[q4][r], t[q4 + 1][r], t[q4 + 2][r], t[q4 + 3][r]};
  *(float4*)(xt + ((long)(l * 4096 + s0 + r) << 7) + c0 + q4) = o;
}

__global__ __launch_bounds__(256) void k_tout(const float* __restrict__ xt,
                                              float* __restrict__ out) {
  __shared__ float t[32][33];
  int s0 = blockIdx.x * 32, c0 = blockIdx.y * 32, l = blockIdx.z;
  int r = threadIdx.x >> 3, q4 = (threadIdx.x & 7) * 4;
  float4 v = *(const float4*)(xt + ((long)(l * 4096 + s0 + r) << 7) + c0 + q4);
  t[r][q4] = v.x; t[r][q4 + 1] = v.y; t[r][q4 + 2] = v.z; t[r][q4 + 3] = v.w;
  __syncthreads();
  float4 o = {t[q4][r], t[q4 + 1][r], t[q4 + 2][r], t[q4 + 3][r]};
  *(float4*)(out + ((long)(l * 128 + c0 + r) << 12) + s0 + q4) = o;
}

__global__ __launch_bounds__(256) void k_zeropage(u16* __restrict__ zp) {
  zp[threadIdx.x] = 0; zp[threadIdx.x + 256] = 0;
  zp[threadIdx.x + 512] = 0; zp[threadIdx.x + 768] = 0;
}

// ---------------- layernorm fp32 in -> bf16 out, one wave per row ----------------
__global__ __launch_bounds__(256) void k_ln_f2b(const float* __restrict__ X,
                                                const float* __restrict__ g,
                                                const float* __restrict__ b,
                                                u16* __restrict__ Y, int M) {
  int n = blockIdx.x * 4 + (threadIdx.x >> 6);
  if (n >= M) return;
  int lane = threadIdx.x & 63;
  const float* row = X + (long)n * 128;
  float2 v = *(const float2*)(row + lane * 2);
  float s = v.x + v.y;
#pragma unroll
  for (int o = 32; o > 0; o >>= 1) s += __shfl_xor(s, o);
  float mu = s * (1.0f / 128.0f);
  float dx = v.x - mu, dy = v.y - mu;
  float q = dx * dx + dy * dy;
#pragma unroll
  for (int o = 32; o > 0; o >>= 1) q += __shfl_xor(q, o);
  float rs = rsqrtf(q * (1.0f / 128.0f) + 1e-5f);
  float2 gv = *(const float2*)(g + lane * 2);
  float2 bv = *(const float2*)(b + lane * 2);
  ushort2 o2;
  o2.x = f2bf(dx * rs * gv.x + bv.x);
  o2.y = f2bf(dy * rs * gv.y + bv.y);
  *(ushort2*)(Y + (long)n * 128 + lane * 2) = o2;
}

// ---------------- coalesced weight repack: W[oc][ic][t] fp32 -> Wb[t][oc][ic] bf16 ----------
__global__ __launch_bounds__(256) void k_repack2(const float* __restrict__ W,
                                                 u16* __restrict__ Wb,
                                                 int OC, int IC, int NT) {
  __shared__ float ws[128 * 81];
  int oc = blockIdx.x, ic0 = blockIdx.y * 128;
  const float* src = W + ((long)oc * IC + ic0) * NT;
  int n = 128 * NT;
  for (int i = threadIdx.x; i < n; i += 256) ws[i] = src[i];
  __syncthreads();
  u16* dst = Wb + (long)oc * IC + ic0;
  long tstep = (long)OC * IC;
  for (int idx = threadIdx.x; idx < n; idx += 256) {
    int t = idx >> 7, i = idx & 127;
    dst[(long)t * tstep + i] = f2bf(ws[i * NT + t]);
  }
}

// ---------------- small conv-as-gather-GEMM (64 x 64 tile) for small M ----------------
__global__ __launch_bounds__(256) void k_conv_mfma(
    const u16* __restrict__ X, const u16* __restrict__ W3,
    const float* __restrict__ bias, void* __restrict__ Yv,
    int M, int IC, int OC, int mode, int NT,
    int lgWo, int lgHo, int lgDo,
    int lgWi, int lgHi, int lgDi,
    int Li, int Di, int Hi, int Wi,
    int sL, int sD, int sH, int sW, int flags) {
  __shared__ u16 As[64 * PITCH];
  __shared__ u16 Bs[64 * PITCH];
  int tid = threadIdx.x;
  int wave = tid >> 6, lane = tid & 63;
  int quad = lane >> 4, l15 = lane & 15;
  int m0 = blockIdx.x * 64;
  int oc0 = blockIdx.y * 64;

  int srl = tid >> 2;
  int sao = (tid & 3) * 8;
  int sboc = tid >> 2, sbo = (tid & 3) * 8;

  int sm = m0 + srl;
  bool mv = sm < M;
  int w = sm & ((1 << lgWo) - 1);
  int h = (sm >> lgWo) & ((1 << lgHo) - 1);
  int d = (sm >> (lgWo + lgHo)) & ((1 << lgDo) - 1);
  int l = sm >> (lgWo + lgHo + lgDo);

  int c0 = 0, c1 = 0, c2 = 0, c3 = 0;
  auto comp_nb = [&]() -> long {
    if (!mv) return -1;
    int li, di, hi, wi; bool ok;
    if (mode == 0) {
      int dl = c0 - 1;
      int ll = (l & 1) + dl;
      ok = (ll >= 0 && ll < 2);
      li = l + dl; di = d; hi = h; wi = w;
    } else if (mode == 1) {
      li = l * sL; di = d * sD + c2 - 1; hi = h * sH + c1 - 1; wi = w * sW + c0 - 1;
      ok = ((unsigned)di < (unsigned)Di) && ((unsigned)hi < (unsigned)Hi) &&
           ((unsigned)wi < (unsigned)Wi);
    } else {
      li = l + c3 - 1; di = d + c2 - 1; hi = h + c1 - 1; wi = w + c0 - 1;
      ok = ((unsigned)li < (unsigned)Li) && ((unsigned)di < (unsigned)Di) &&
           ((unsigned)hi < (unsigned)Hi) && ((unsigned)wi < (unsigned)Wi);
    }
    if (!ok) return -1;
    return ((((long)((li << lgDi) + di) << lgHi) + hi) << lgWi) + wi;
  };

  long nb = comp_nb();
  const u16* wt = W3 + (long)(oc0 + sboc) * IC + sbo;
  long wstep = (long)OC * IC;
  int kmask = (IC >> 5) - 1;
  int total = NT * (IC >> 5);

  const bf16x8 Z = {0, 0, 0, 0, 0, 0, 0, 0};
  bf16x8 ra0 = Z, rb;
  if (nb >= 0) ra0 = *(const bf16x8*)(X + nb * IC + sao);
  rb = *(const bf16x8*)wt;

  f32x4 acc[4];
#pragma unroll
  for (int j = 0; j < 4; ++j) acc[j] = {0.f, 0.f, 0.f, 0.f};

  int wrow = wave * 16;

  for (int ks = 0; ks < total; ++ks) {
    __syncthreads();
    *(bf16x8*)&As[srl * PITCH + sao] = ra0;
    *(bf16x8*)&Bs[sboc * PITCH + sbo] = rb;
    __syncthreads();
    int ksn = ks + 1;
    if (ksn < total) {
      int k0n = (ksn & kmask) << 5;
      if ((ksn & kmask) == 0) {
        wt += wstep;
        if (++c0 == 3) { c0 = 0; if (++c1 == 3) { c1 = 0; if (++c2 == 3) { c2 = 0; ++c3; } } }
        nb = comp_nb();
      }
      ra0 = Z;
      if (nb >= 0) ra0 = *(const bf16x8*)(X + nb * IC + k0n + sao);
      rb = *(const bf16x8*)(wt + k0n);
    }
    bf16x8 a0 = *(const bf16x8*)&As[(wrow + l15) * PITCH + quad * 8];
#pragma unroll
    for (int j = 0; j < 4; ++j) {
      bf16x8 b = *(const bf16x8*)&Bs[(j * 16 + l15) * PITCH + quad * 8];
      acc[j] = __builtin_amdgcn_mfma_f32_16x16x32_bf16(a0, b, acc[j], 0, 0, 0);
    }
  }

  int col = oc0 + l15;
#pragma unroll
  for (int j = 0; j < 4; ++j) {
    float bj = bias[col + j * 16];
    int rbase = m0 + wrow + quad * 4;
#pragma unroll
    for (int r = 0; r < 4; ++r) {
      int row = rbase + r;
      if (row >= M) continue;
      float v = acc[j][r] + bj;
      if (flags & 2) v = fmaxf(v, 0.f);
      long off = (long)row * OC + col + j * 16;
      if (flags & 4) ((u16*)Yv)[off] = f2bf(v);
      else if (flags & 1) ((float*)Yv)[off] += v;
      else ((float*)Yv)[off] = v;
    }
  }
}

// ---------------- big conv-GEMM: 128x128 tile, BK=64, single-buffer global_load_lds ----------
__global__ __launch_bounds__(256, 4) void k_conv_gl(
    const u16* __restrict__ X, const u16* __restrict__ W3,
    const float* __restrict__ bias, void* __restrict__ Yv, float* __restrict__ SP,
    const u16* __restrict__ ZP,
    int M, int IC, int OC, int mode, int NT, int NSPLIT,
    int lgWo, int lgHo, int lgDo,
    int lgWi, int lgHi, int lgDi,
    int Li, int Di, int Hi, int Wi,
    int sL, int sD, int sH, int sW, int flags) {
  __shared__ __align__(16) u16 As[128 * 64];
  __shared__ __align__(16) u16 Bs[128 * 64];
  int tid = threadIdx.x;
  int wave = tid >> 6, lane = tid & 63;
  int quad = lane >> 4, l15 = lane & 15;
  int m0 = blockIdx.x * 128, oc0 = blockIdx.y * 128;
  int mi = wave & 1, ni = wave >> 1;

  int rp[4], cA[4], sm[4];
#pragma unroll
  for (int q = 0; q < 4; ++q) {
    rp[q] = wave * 32 + q * 8 + (lane >> 3);
    cA[q] = ((lane & 7) - (rp[q] >> 1)) & 7;
    sm[q] = m0 + rp[q];
  }

  int tap_per = (NT + NSPLIT - 1) / NSPLIT;
  int t0 = blockIdx.z * tap_per;
  int t1 = min(NT, t0 + tap_per);
  int kc = IC >> 6;
  int total = (t1 - t0) * kc;

  int c0 = t0 % 3, c1 = (t0 / 3) % 3, c2 = (t0 / 9) % 3, c3 = t0 / 27;
  auto comp_nb = [&](int smv) -> int {
    if (smv >= M) return -1;
    int w = smv & ((1 << lgWo) - 1);
    int h = (smv >> lgWo) & ((1 << lgHo) - 1);
    int d = (smv >> (lgWo + lgHo)) & ((1 << lgDo) - 1);
    int l = smv >> (lgWo + lgHo + lgDo);
    int li, di, hi, wi; bool ok;
    if (mode == 0) {
      int dl = c0 - 1;
      int ll = (l & 1) + dl;
      ok = (ll >= 0 && ll < 2);
      li = l + dl; di = d; hi = h; wi = w;
    } else if (mode == 1) {
      li = l * sL; di = d * sD + c2 - 1; hi = h * sH + c1 - 1; wi = w * sW + c0 - 1;
      ok = ((unsigned)di < (unsigned)Di) && ((unsigned)hi < (unsigned)Hi) &&
           ((unsigned)wi < (unsigned)Wi);
    } else {
      li = l + c3 - 1; di = d + c2 - 1; hi = h + c1 - 1; wi = w + c0 - 1;
      ok = ((unsigned)li < (unsigned)Li) && ((unsigned)di < (unsigned)Di) &&
           ((unsigned)hi < (unsigned)Hi) && ((unsigned)wi < (unsigned)Wi);
    }
    if (!ok) return -1;
    return (((li << lgDi) + di) << lgHi | hi) << lgWi | wi;
  };

  int nb[4];
#pragma unroll
  for (int q = 0; q < 4; ++q) nb[q] = comp_nb(sm[q]);
  long wstep = (long)OC * IC;
  const u16* wbase = W3 + (long)t0 * wstep + (long)oc0 * IC;

  f32x4 acc[4][4];
#pragma unroll
  for (int i = 0; i < 4; ++i)
#pragma unroll
    for (int j = 0; j < 4; ++j) acc[i][j] = {0.f, 0.f, 0.f, 0.f};

  int kk = 0;
  for (int ks = 0; ks < total; ++ks) {
    if (kk == kc) {
      kk = 0;
      if (++c0 == 3) { c0 = 0; if (++c1 == 3) { c1 = 0; if (++c2 == 3) { c2 = 0; ++c3; } } }
#pragma unroll
      for (int q = 0; q < 4; ++q) nb[q] = comp_nb(sm[q]);
      wbase += wstep;
    }
    int k0 = kk << 6;
    ++kk;
    __syncthreads();
#pragma unroll
    for (int q = 0; q < 4; ++q) {
      const u16* a = (nb[q] >= 0) ? X + (long)nb[q] * IC + k0 + cA[q] * 8 : ZP;
      gll16(a, &As[(wave * 4 + q) * 512]);
    }
#pragma unroll
    for (int q = 0; q < 4; ++q) {
      const u16* bsrc = wbase + (long)rp[q] * IC + k0 + cA[q] * 8;
      gll16(bsrc, &Bs[(wave * 4 + q) * 512]);
    }
    __syncthreads();
#pragma unroll
    for (int ksub = 0; ksub < 2; ++ksub) {
      bf16x8 af[4], bf[4];
#pragma unroll
      for (int i = 0; i < 4; ++i) {
        int row = mi * 64 + i * 16 + l15;
        int pa = ((ksub * 4 + quad) + (row >> 1)) & 7;
        af[i] = *(const bf16x8*)&As[row * 64 + pa * 8];
      }
#pragma unroll
      for (int j = 0; j < 4; ++j) {
        int row = ni * 64 + j * 16 + l15;
        int pb = ((ksub * 4 + quad) + (row >> 1)) & 7;
        bf[j] = *(const bf16x8*)&Bs[row * 64 + pb * 8];
      }
#pragma unroll
      for (int i = 0; i < 4; ++i)
#pragma unroll
        for (int j = 0; j < 4; ++j)
          acc[i][j] = __builtin_amdgcn_mfma_f32_16x16x32_bf16(af[i], bf[j], acc[i][j], 0, 0, 0);
    }
  }

  if (NSPLIT > 1) {
    float* out = SP + (long)blockIdx.z * M * OC;
#pragma unroll
    for (int j = 0; j < 4; ++j) {
      int c = oc0 + ni * 64 + j * 16 + l15;
#pragma unroll
      for (int i = 0; i < 4; ++i) {
        int rbase = m0 + mi * 64 + i * 16 + quad * 4;
#pragma unroll
        for (int r = 0; r < 4; ++r) {
          int row = rbase + r;
          if (row < M) out[(long)row * OC + c] = acc[i][j][r];
        }
      }
    }
  } else {
#pragma unroll
    for (int j = 0; j < 4; ++j) {
      int c = oc0 + ni * 64 + j * 16 + l15;
      float bj = bias[c];
#pragma unroll
      for (int i = 0; i < 4; ++i) {
        int rbase = m0 + mi * 64 + i * 16 + quad * 4;
#pragma unroll
        for (int r = 0; r < 4; ++r) {
          int row = rbase + r;
          if (row >= M) continue;
          float v = acc[i][j][r] + bj;
          if (flags & 2) v = fmaxf(v, 0.f);
          long off = (long)row * OC + c;
          if (flags & 4) ((u16*)Yv)[off] = f2bf(v);
          else if (flags & 1) ((float*)Yv)[off] += v;
          else ((float*)Yv)[off] = v;
        }
      }
    }
  }
}

// ---------------- 256x256 8-phase conv-GEMM (T2+T3+T4+T5), BK=64, 8 waves ----------------
// Round-3 fix vs round-2: REMOVED the explicit "s_waitcnt lgkmcnt(0)" + sched_barrier(0)
// between the phase barrier and the MFMA cluster. The ds_reads are plain C++ loads, so the
// compiler emits minimal counted lgkmcnt(N) before each dependent MFMA -> the LDS drain of
// the 8-12 phase reads now overlaps the MFMA cluster instead of fully serializing (R2 was
// drain->MFMA serial at ~1390 cyc/phase vs 512 cyc MFMA work). Reads are issued in
// consumption order (af0, b0..b3, af1..af3). Read-issue remains pinned before the barrier
// via sched_barrier(0); vmcnt(8) counted, never 0 in loop.
__global__ __launch_bounds__(512, 2) void k_conv_g256(
    const u16* __restrict__ X, const u16* __restrict__ W3,
    const float* __restrict__ bias, void* __restrict__ Yv, float* __restrict__ SP,
    const u16* __restrict__ ZP,
    int M, int IC, int OC, int mode, int NT, int NSPLIT,
    int lgWo, int lgHo, int lgDo,
    int lgWi, int lgHi, int lgDi,
    int Li, int Di, int Hi, int Wi,
    int sL, int sD, int sH, int sW, int flags) {
  __shared__ __align__(16) u16 Ab[4][8192];   // 64 KiB, region = buf*2+ks
  __shared__ __align__(16) u16 Bb[4][8192];   // 64 KiB
  int tid = threadIdx.x;
  int wave = tid >> 6, lane = tid & 63;
  int quad = lane >> 4, l15 = lane & 15;
  int wr = wave >> 2, wc = wave & 3;
  int m0 = blockIdx.x * 256, oc0 = blockIdx.y * 256;

  // staging geometry: thread covers rows srow0 and srow0+128, 16B phys chunk spc
  int srow0 = tid >> 2;
  int spc = tid & 3;
  int lc0 = (spc - (srow0 >> 1)) & 3;          // logical k-chunk at this slot
  int lc1 = (spc - ((srow0 + 128) >> 1)) & 3;

  int kc = IC >> 6;
  int hsPerTap = kc << 1;
  int tap_per = (NT + NSPLIT - 1) / NSPLIT;
  int t0 = blockIdx.z * tap_per;
  int t1 = min(NT, t0 + tap_per);
  int TOT = (t1 - t0) * kc;
  int TOTH = TOT * 2;

  int c0 = t0 % 3, c1 = (t0 / 3) % 3, c2 = (t0 / 9) % 3, c3 = t0 / 27;
  auto comp_nb = [&](int smv) -> int {
    if (smv >= M) return -1;
    int w = smv & ((1 << lgWo) - 1);
    int h = (smv >> lgWo) & ((1 << lgHo) - 1);
    int d = (smv >> (lgWo + lgHo)) & ((1 << lgDo) - 1);
    int l = smv >> (lgWo + lgHo + lgDo);
    int li, di, hi, wi; bool ok;
    if (mode == 0) {
      int dl = c0 - 1;
      int ll = (l & 1) + dl;
      ok = (ll >= 0 && ll < 2);
      li = l + dl; di = d; hi = h; wi = w;
    } else if (mode == 1) {
      li = l * sL; di = d * sD + c2 - 1; hi = h * sH + c1 - 1; wi = w * sW + c0 - 1;
      ok = ((unsigned)di < (unsigned)Di) && ((unsigned)hi < (unsigned)Hi) &&
           ((unsigned)wi < (unsigned)Wi);
    } else {
      li = l + c3 - 1; di = d + c2 - 1; hi = h + c1 - 1; wi = w + c0 - 1;
      ok = ((unsigned)li < (unsigned)Li) && ((unsigned)di < (unsigned)Di) &&
           ((unsigned)hi < (unsigned)Hi) && ((unsigned)wi < (unsigned)Wi);
    }
    if (!ok) return -1;
    return (((li << lgDi) + di) << lgHi | hi) << lgWi | wi;
  };

  // ---- A staging state (gather; recompute on tap change only) ----
  int nb0 = comp_nb(m0 + srow0);
  int nb1 = comp_nb(m0 + srow0 + 128);
  const u16* ap0;
  const u16* ap1;
  auto setAp = [&]() {
    ap0 = (nb0 >= 0) ? X + (long)nb0 * IC + lc0 * 8 : ZP;
    ap1 = (nb1 >= 0) ? X + (long)nb1 * IC + lc1 * 8 : ZP;
  };
  setAp();
  int ahs = 0, sA = 0;
  u16* adst = &Ab[0][wave << 9];
  auto stageA = [&]() {
    u16* d = adst + ((sA & 3) << 13);
    ++sA;
    if (sA > TOTH) { gll16(ZP, d); gll16(ZP, d + 4096); return; }
    gll16(ap0 + (ahs << 5), d);
    gll16(ap1 + (ahs << 5), d + 4096);
    if (++ahs == hsPerTap) {
      ahs = 0;
      if (++c0 == 3) { c0 = 0; if (++c1 == 3) { c1 = 0; if (++c2 == 3) { c2 = 0; ++c3; } } }
      nb0 = comp_nb(m0 + srow0);
      nb1 = comp_nb(m0 + srow0 + 128);
      setAp();
    }
  };

  // ---- B staging state (rolling pointer) ----
  long wstep = (long)OC * IC;
  const u16* bp = W3 + ((long)t0 * OC + oc0 + srow0) * IC + lc0 * 8;
  long bdlt = (long)128 * IC + (lc1 - lc0) * 8;
  long btap = wstep - (long)(hsPerTap - 1) * 32;
  int bhs = 0, sB = 0;
  u16* bdst = &Bb[0][wave << 9];
  auto stageB = [&]() {
    u16* d = bdst + ((sB & 3) << 13);
    ++sB;
    if (sB > TOTH) { gll16(ZP, d); gll16(ZP, d + 4096); return; }
    gll16(bp, d);
    gll16(bp + bdlt, d + 4096);
    if (++bhs == hsPerTap) { bhs = 0; bp += btap; }
    else bp += 32;
  };

  // ---- precomputed LDS read bases (swizzle chunk invariant under row+16/+64) ----
  int rowA0 = (wr << 7) + l15;
  int rA0 = rowA0 * 32 + (((quad + (rowA0 >> 1)) & 3) << 3);
  int rowB0 = (wc << 6) + l15;
  int rB0 = rowB0 * 32 + (((quad + (rowB0 >> 1)) & 3) << 3);
  const u16* Abase = &Ab[0][0];
  const u16* Bbase = &Bb[0][0];

  f32x4 acc[8][4];
#pragma unroll
  for (int i = 0; i < 8; ++i)
#pragma unroll
    for (int j = 0; j < 4; ++j) acc[i][j] = {0.f, 0.f, 0.f, 0.f};

  bf16x8 af[4], bfr[4];
  // combined read in consumption order: af0, b0..b3, af1..af3
  auto rdAB = [&](int reg) {
    const u16* pA = Abase + (reg << 13) + rA0;
    const u16* pB = Bbase + (reg << 13) + rB0;
    af[0] = *(const bf16x8*)(pA);
    bfr[0] = *(const bf16x8*)(pB);
    bfr[1] = *(const bf16x8*)(pB + (1 << 9));
    bfr[2] = *(const bf16x8*)(pB + (2 << 9));
    bfr[3] = *(const bf16x8*)(pB + (3 << 9));
    af[1] = *(const bf16x8*)(pA + (1 << 9));
    af[2] = *(const bf16x8*)(pA + (2 << 9));
    af[3] = *(const bf16x8*)(pA + (3 << 9));
  };
  auto rdA = [&](int reg, int ih) {
    const u16* pA = Abase + (reg << 13) + (ih << 11) + rA0;
#pragma unroll
    for (int i = 0; i < 4; ++i) af[i] = *(const bf16x8*)(pA + (i << 9));
  };
  auto mf = [&](int ih) {
    __builtin_amdgcn_s_setprio(1);
#pragma unroll
    for (int i = 0; i < 4; ++i)
#pragma unroll
      for (int j = 0; j < 4; ++j)
        acc[(ih << 2) + i][j] =
            __builtin_amdgcn_mfma_f32_16x16x32_bf16(af[i], bfr[j], acc[(ih << 2) + i][j], 0, 0, 0);
    __builtin_amdgcn_s_setprio(0);
  };

  // prologue: stage s=0..2 for A and B (interleaved A,B,A,B,A,B = 12 loads);
  // vmcnt(8) completes the 4 oldest = A(0,0),B(0,0)
  stageA(); stageB();
  stageA(); stageB();
  stageA(); stageB();
  asm volatile("s_waitcnt vmcnt(8)" ::: "memory");
  __builtin_amdgcn_s_barrier();

  for (int n = 0; n < TOT; ++n) {
    int rg = (n & 1) << 1;
    // ---- phase 0: ks=0, i-half 0 ----
    rdAB(rg);
    stageA();                                   // (n+1, ks=1)
    __builtin_amdgcn_sched_barrier(0);
    __builtin_amdgcn_s_barrier();
    mf(0);                                      // compiler-counted lgkmcnt interleave
    __builtin_amdgcn_s_barrier();
    // ---- phase 1: ks=0, i-half 1 (B reused in regs) ----
    rdA(rg, 1);
    stageB();                                   // (n+1, ks=1)
    __builtin_amdgcn_sched_barrier(0);
    __builtin_amdgcn_s_barrier();
    mf(1);
    __builtin_amdgcn_sched_barrier(0);
    asm volatile("s_waitcnt vmcnt(8)" ::: "memory");
    __builtin_amdgcn_s_barrier();
    // ---- phase 2: ks=1, i-half 0 ----
    rdAB(rg + 1);
    stageA();                                   // (n+2, ks=0)
    __builtin_amdgcn_sched_barrier(0);
    __builtin_amdgcn_s_barrier();
    mf(0);
    __builtin_amdgcn_s_barrier();
    // ---- phase 3: ks=1, i-half 1 ----
    rdA(rg + 1, 1);
    stageB();                                   // (n+2, ks=0)
    __builtin_amdgcn_sched_barrier(0);
    __builtin_amdgcn_s_barrier();
    mf(1);
    __builtin_amdgcn_sched_barrier(0);
    asm volatile("s_waitcnt vmcnt(8)" ::: "memory");
    __builtin_amdgcn_s_barrier();
  }

  // epilogue: C/D layout col=l15, row=quad*4+r
  if (NSPLIT > 1) {
    float* outp = SP + (long)blockIdx.z * M * OC;
#pragma unroll
    for (int i = 0; i < 8; ++i)
#pragma unroll
      for (int j = 0; j < 4; ++j) {
        int c = oc0 + (wc << 6) + (j << 4) + l15;
        int rb = m0 + (wr << 7) + (i << 4) + (quad << 2);
#pragma unroll
        for (int r = 0; r < 4; ++r) {
          int row = rb + r;
          if (row < M) outp[(long)row * OC + c] = acc[i][j][r];
        }
      }
  } else {
#pragma unroll
    for (int i = 0; i < 8; ++i)
#pragma unroll
      for (int j = 0; j < 4; ++j) {
        int c = oc0 + (wc << 6) + (j << 4) + l15;
        float bj = bias[c];
        int rb = m0 + (wr << 7) + (i << 4) + (quad << 2);
#pragma unroll
        for (int r = 0; r < 4; ++r) {
          int row = rb + r;
          if (row >= M) continue;
          float v = acc[i][j][r] + bj;
          if (flags & 2) v = fmaxf(v, 0.f);
          long off = (long)row * OC + c;
          if (flags & 4) ((u16*)Yv)[off] = f2bf(v);
          else if (flags & 1) ((float*)Yv)[off] += v;
          else ((float*)Yv)[off] = v;
        }
      }
  }
}

// ---------------- combine split-K partials: out = (sum_s SP[s]) + bias ----------------
__global__ __launch_bounds__(256) void k_combine(const float* __restrict__ SP,
                                                 const float* __restrict__ bias,
                                                 void* __restrict__ out,
                                                 long MOC, int lgOC, int nsplit, int flags) {
  long idx = (long)blockIdx.x * 256 + threadIdx.x;
  if (idx >= MOC) return;
  float v = bias[idx & ((1 << lgOC) - 1)];
  for (int s = 0; s < nsplit; ++s) v += SP[s * MOC + idx];
  if (flags & 2) v = fmaxf(v, 0.f);
  if (flags & 4) ((u16*)out)[idx] = f2bf(v);
  else if (flags & 1) ((float*)out)[idx] += v;
  else ((float*)out)[idx] = v;
}

// ---------------- TLG windowed cross attention: 8q x 8k per (window, head), bf16 ----------------
__global__ __launch_bounds__(256) void k_tlg_attn(const u16* __restrict__ Q,
                                                  const u16* __restrict__ K,
                                                  const u16* __restrict__ V,
                                                  u16* __restrict__ Y) {
  int gw = blockIdx.x * 4 + (threadIdx.x >> 6);
  int lane = threadIdx.x & 63;
  int head = gw & 7;
  int win = gw >> 3;
  int wB = win & 7, hB = (win >> 3) & 7, dB = (win >> 6) & 7, l = win >> 9;
  int i = lane >> 3, j = lane & 7;
  int nq = (l << 12) | ((dB * 2 + (i >> 2)) << 8) | ((hB * 2 + ((i >> 1) & 1)) << 4) |
           (wB * 2 + (i & 1));
  int lk = l ^ 2;
  int nk = (lk << 12) | ((dB * 2 + (j >> 2)) << 8) | ((hB * 2 + ((j >> 1) & 1)) << 4) |
           (wB * 2 + (j & 1));
  int hoff = head * 16;
  const u16* qp = Q + (long)nq * 128 + hoff;
  const u16* kp = K + (long)nk * 128 + hoff;
  float s = 0.f;
#pragma unroll
  for (int t = 0; t < 16; t += 4) {
    float4 a = load4bf(qp + t);
    float4 b = load4bf(kp + t);
    s += a.x * b.x + a.y * b.y + a.z * b.z + a.w * b.w;
  }
  s *= 0.25f;
  float mx = s;
#pragma unroll
  for (int o = 1; o < 8; o <<= 1) mx = fmaxf(mx, __shfl_xor(mx, o));
  float e = __expf(s - mx);
  float sum = e;
#pragma unroll
  for (int o = 1; o < 8; o <<= 1) sum += __shfl_xor(sum, o);
  float p = e / sum;
  const u16* vp = V + (long)nk * 128 + hoff;
  float y[16];
#pragma unroll
  for (int t = 0; t < 16; t += 4) {
    float4 vv = load4bf(vp + t);
    y[t] = p * vv.x; y[t + 1] = p * vv.y; y[t + 2] = p * vv.z; y[t + 3] = p * vv.w;
  }
#pragma unroll
  for (int o = 1; o < 8; o <<= 1) {
#pragma unroll
    for (int t = 0; t < 16; ++t) y[t] += __shfl_xor(y[t], o);
  }
  if (j == 0) {
    u16* yp = Y + (long)nq * 128 + hoff;
    u16 tmp[16];
#pragma unroll
    for (int t = 0; t < 16; ++t) tmp[t] = f2bf(y[t]);
    *(uint4*)(yp) = *(uint4*)tmp;
    *(uint4*)(yp + 8) = *(uint4*)(tmp + 8);
  }
}

// ---------------- SLG K/V repack for flash attn ----------------
__global__ __launch_bounds__(256) void k_pack_kh(const u16* __restrict__ Kin,
                                                 u16* __restrict__ Kh) {
  int idx = blockIdx.x * 256 + threadIdx.x;
  if (idx >= 8 * 1032 * 16) return;
  int d = idx & 15;
  int r = idx >> 4;
  int k = r % 1032, h = r / 1032;
  Kh[idx] = Kin[k * 128 + h * 16 + d];
}
__global__ __launch_bounds__(256) void k_pack_vt(const u16* __restrict__ Vin,
                                                 u16* __restrict__ Vt) {
  int idx = blockIdx.x * 256 + threadIdx.x;
  if (idx >= 8 * 16 * 1032) return;
  int k = idx % 1032;
  int r = idx / 1032;
  int d = r & 15, h = r >> 4;
  Vt[idx] = Vin[k * 128 + h * 16 + d];
}

// ---------------- SLG MFMA flash attention ----------------
__global__ __launch_bounds__(256) void k_slg_flash(const u16* __restrict__ Q,
                                                   const u16* __restrict__ Kh,
                                                   const u16* __restrict__ Vt,
                                                   u16* __restrict__ Y) {
  constexpr int NK = 1032;
  constexpr int NTILE = 17;
  __shared__ __align__(16) u16 Ks[64 * 24];
  __shared__ __align__(16) u16 Vs[16 * 72];
  __shared__ __align__(16) u16 Ps[4][16 * 72];
  int tid = threadIdx.x;
  int wave = tid >> 6, lane = tid & 63;
  int quad = lane >> 4, l15 = lane & 15;
  int h = blockIdx.x & 7;
  int q0 = (blockIdx.x >> 3) * 64 + wave * 16;

  const bf16x8 Zb = {0, 0, 0, 0, 0, 0, 0, 0};
  bf16x8 qf = Zb;
  if (quad < 2) qf = *(const bf16x8*)(Q + (long)(q0 + l15) * 128 + h * 16 + quad * 8);

  const u16* Kbase = Kh + (long)h * NK * 16;
  const u16* Vbase = Vt + (long)h * 16 * NK;

  float mrow[4], lrow[4];
  f32x4 oacc = {0.f, 0.f, 0.f, 0.f};
#pragma unroll
  for (int r = 0; r < 4; ++r) { mrow[r] = -1e30f; lrow[r] = 0.f; }

  int skey = tid >> 2, sch = (tid & 3) * 4;
  int svd = tid >> 4, svc = (tid & 15) * 4;

  for (int t = 0; t < NTILE; ++t) {
    int k0 = t * 64;
    __syncthreads();
    {
      short4 v = {0, 0, 0, 0};
      int key = k0 + skey;
      if (key < NK) v = *(const short4*)(Kbase + key * 16 + sch);
      *(short4*)&Ks[skey * 24 + sch] = v;
    }
    {
      short4 v = {0, 0, 0, 0};
      int colb = k0 + svc;
      if (colb < NK) v = *(const short4*)(Vbase + svd * NK + colb);
      *(short4*)&Vs[svd * 72 + svc] = v;
    }
    __syncthreads();

    f32x4 s[4];
#pragma unroll
    for (int sub = 0; sub < 4; ++sub) {
      bf16x8 b = Zb;
      if (quad < 2) b = *(const bf16x8*)&Ks[(sub * 16 + l15) * 24 + quad * 8];
      f32x4 zero = {0.f, 0.f, 0.f, 0.f};
      s[sub] = __builtin_amdgcn_mfma_f32_16x16x32_bf16(qf, b, zero, 0, 0, 0);
    }
    float pv[4][4];
    float tmax[4] = {-1e30f, -1e30f, -1e30f, -1e30f};
#pragma unroll
    for (int sub = 0; sub < 4; ++sub) {
      int key = k0 + sub * 16 + l15;
      bool valid = key < NK;
#pragma unroll
      for (int r = 0; r < 4; ++r) {
        float sv = valid ? s[sub][r] * 0.25f : -1e30f;
        pv[sub][r] = sv;
        tmax[r] = fmaxf(tmax[r], sv);
      }
    }
#pragma unroll
    for (int o = 1; o < 16; o <<= 1)
#pragma unroll
      for (int r = 0; r < 4; ++r) tmax[r] = fmaxf(tmax[r], __shfl_xor(tmax[r], o));

    float al[4], tsum[4] = {0.f, 0.f, 0.f, 0.f};
#pragma unroll
    for (int r = 0; r < 4; ++r) {
      float mn = fmaxf(mrow[r], tmax[r]);
      al[r] = __expf(mrow[r] - mn);
      mrow[r] = mn;
    }
#pragma unroll
    for (int sub = 0; sub < 4; ++sub)
#pragma unroll
      for (int r = 0; r < 4; ++r) {
        float pe = __expf(pv[sub][r] - mrow[r]);
        tsum[r] += pe;
        Ps[wave][(quad * 4 + r) * 72 + sub * 16 + l15] = f2bf(pe);
      }
#pragma unroll
    for (int o = 1; o < 16; o <<= 1)
#pragma unroll
      for (int r = 0; r < 4; ++r) tsum[r] += __shfl_xor(tsum[r], o);
#pragma unroll
    for (int r = 0; r < 4; ++r) {
      lrow[r] = lrow[r] * al[r] + tsum[r];
      oacc[r] *= al[r];
    }
    bf16x8 pa0 = *(const bf16x8*)&Ps[wave][l15 * 72 + quad * 8];
    bf16x8 pa1 = *(const bf16x8*)&Ps[wave][l15 * 72 + 32 + quad * 8];
    bf16x8 vb0 = *(const bf16x8*)&Vs[l15 * 72 + quad * 8];
    bf16x8 vb1 = *(const bf16x8*)&Vs[l15 * 72 + 32 + quad * 8];
    oacc = __builtin_amdgcn_mfma_f32_16x16x32_bf16(pa0, vb0, oacc, 0, 0, 0);
    oacc = __builtin_amdgcn_mfma_f32_16x16x32_bf16(pa1, vb1, oacc, 0, 0, 0);
  }

#pragma unroll
  for (int r = 0; r < 4; ++r) {
    float inv = 1.0f / lrow[r];
    Y[(long)(q0 + quad * 4 + r) * 128 + h * 16 + l15] = f2bf(oacc[r] * inv);
  }
}

static inline int ilg(int v) { int r = 0; while ((1 << r) < v) ++r; return r; }

extern "C" void kernel_launch(void* const* d_in, const int* in_sizes, int n_in,
                              void* d_out, int out_size, void* d_ws, size_t ws_size,
                              hipStream_t stream) {
  (void)in_sizes; (void)n_in; (void)out_size; (void)ws_size;
  const float* x    = (const float*)d_in[0];
  const float* n1_w = (const float*)d_in[1];  const float* n1_b = (const float*)d_in[2];
  const float* n2_w = (const float*)d_in[3];  const float* n2_b = (const float*)d_in[4];
  const float* n3_w = (const float*)d_in[5];  const float* n3_b = (const float*)d_in[6];
  const float* sn_w = (const float*)d_in[7];  const float* sn_b = (const float*)d_in[8];
  const float* tq_w = (const float*)d_in[9];  const float* tq_b = (const float*)d_in[10];
  const float* tk_w = (const float*)d_in[11]; const float* tk_b = (const float*)d_in[12];
  const float* tv_w = (const float*)d_in[13]; const float* tv_b = (const float*)d_in[14];
  const float* tp_w = (const float*)d_in[15]; const float* tp_b = (const float*)d_in[16];
  const float* sq_w = (const float*)d_in[17]; const float* sq_b = (const float*)d_in[18];
  const float* sk_w = (const float*)d_in[19]; const float* sk_b = (const float*)d_in[20];
  const float* sv_w = (const float*)d_in[21]; const float* sv_b = (const float*)d_in[22];
  const float* sp_w = (const float*)d_in[23]; const float* sp_b = (const float*)d_in[24];
  const float* sf_w = (const float*)d_in[25]; const float* sf_b = (const float*)d_in[26];
  const float* sc_w = (const float*)d_in[27]; const float* sc_b = (const float*)d_in[28];
  const float* m1_w = (const float*)d_in[29]; const float* m1_b = (const float*)d_in[30];
  const float* m2_w = (const float*)d_in[31]; const float* m2_b = (const float*)d_in[32];

  char* p = (char*)d_ws;
  auto alloc = [&](size_t bytes) { char* r = p; p += (bytes + 255) & ~(size_t)255; return r; };
  const long N = 16384;
  float* X0 = (float*)alloc(N * 128 * 4);
  u16* XN = (u16*)alloc(N * 128 * 2);
  u16* Qb = (u16*)alloc(N * 128 * 2);
  u16* Kb = (u16*)alloc(N * 128 * 2);
  u16* Vb = (u16*)alloc(N * 128 * 2);
  u16* Yb = (u16*)alloc(N * 128 * 2);
  u16* H  = (u16*)alloc(N * 512 * 2);
  u16* XC = (u16*)alloc(8 * 128 * 2);
  u16* XF = (u16*)alloc(1024 * 128 * 2);
  float* Kf = (float*)alloc(1032 * 128 * 4);
  float* Vf = (float*)alloc(1032 * 128 * 4);
  u16* Kh = (u16*)alloc(8 * 1032 * 16 * 2);
  u16* Vt = (u16*)alloc(8 * 16 * 1032 * 2);
  float* SPb = (float*)alloc(2L * N * 512 * 4);  // split-K partials (64 MB)
  u16* ZPb = (u16*)alloc(2048);                   // zero page for masked gather rows
  u16* tq2 = (u16*)alloc(49152 * 2);  u16* tk2 = (u16*)alloc(49152 * 2);
  u16* tv2 = (u16*)alloc(49152 * 2);  u16* tp2 = (u16*)alloc(49152 * 2);
  u16* sq2 = (u16*)alloc(442368 * 2); u16* sk2 = (u16*)alloc(442368 * 2);
  u16* sv2 = (u16*)alloc(442368 * 2); u16* sp2 = (u16*)alloc(442368 * 2);
  u16* sf2 = (u16*)alloc(442368 * 2); u16* sc2 = (u16*)alloc(442368 * 2);
  u16* m12 = (u16*)alloc(5308416L * 2);
  u16* m22 = (u16*)alloc(5308416L * 2);

  k_zeropage<<<1, 256, 0, stream>>>(ZPb);

  auto rp = [&](const float* W, u16* Wb, int OC, int IC, int NT) {
    dim3 g(OC, IC / 128);
    k_repack2<<<g, 256, 0, stream>>>(W, Wb, OC, IC, NT);
  };
  rp(tq_w, tq2, 128, 128, 3);  rp(tk_w, tk2, 128, 128, 3);
  rp(tv_w, tv2, 128, 128, 3);  rp(tp_w, tp2, 128, 128, 3);
  rp(sq_w, sq2, 128, 128, 27); rp(sk_w, sk2, 128, 128, 27);
  rp(sv_w, sv2, 128, 128, 27); rp(sp_w, sp2, 128, 128, 27);
  rp(sf_w, sf2, 128, 128, 27); rp(sc_w, sc2, 128, 128, 27);
  rp(m1_w, m12, 512, 128, 81); rp(m2_w, m22, 128, 512, 81);

  auto conv = [&](const u16* Xp, const u16* Wp, const float* Bp, void* Yp,
                  int M, int IC, int OC, int mode, int NT,
                  int Do, int Ho, int Wo, int Li, int Di, int Hi, int Wi,
                  int sL, int sD, int sH, int sW, int flags) {
    int lgWo = ilg(Wo), lgHo = ilg(Ho), lgDo = ilg(Do);
    int lgWi = ilg(Wi), lgHi = ilg(Hi), lgDi = ilg(Di);
    dim3 g((M + 63) / 64, OC / 64);
    k_conv_mfma<<<g, 256, 0, stream>>>(Xp, Wp, Bp, Yp, M, IC, OC, mode, NT,
                                       lgWo, lgHo, lgDo, lgWi, lgHi, lgDi,
                                       Li, Di, Hi, Wi, sL, sD, sH, sW, flags);
  };
  auto conv_gl = [&](const u16* Xp, const u16* Wp, const float* Bp, void* Yp,
                     int M, int IC, int OC, int mode, int NT, int nsplit, int flags) {
    dim3 g(M / 128, OC / 128, nsplit);
    k_conv_gl<<<g, 256, 0, stream>>>(Xp, Wp, Bp, Yp, SPb, ZPb, M, IC, OC, mode, NT, nsplit,
                                     4, 4, 4, 4, 4, 4, 4, 16, 16, 16, 1, 1, 1, 1, flags);
    if (nsplit > 1) {
      long MOC = (long)M * OC;
      k_combine<<<(int)((MOC + 255) / 256), 256, 0, stream>>>(SPb, Bp, Yp, MOC, ilg(OC),
                                                              nsplit, flags);
    }
  };
  // 256x256 8-phase kernel (needs M%256==0 and OC%256==0)
  auto conv_gl256 = [&](const u16* Xp, const u16* Wp, const float* Bp, void* Yp,
                        int M, int IC, int OC, int mode, int NT, int nsplit, int flags) {
    dim3 g(M / 256, OC / 256, nsplit);
    k_conv_g256<<<g, 512, 0, stream>>>(Xp, Wp, Bp, Yp, SPb, ZPb, M, IC, OC, mode, NT, nsplit,
                                       4, 4, 4, 4, 4, 4, 4, 16, 16, 16, 1, 1, 1, 1, flags);
    if (nsplit > 1) {
      long MOC = (long)M * OC;
      k_combine<<<(int)((MOC + 255) / 256), 256, 0, stream>>>(SPb, Bp, Yp, MOC, ilg(OC),
                                                              nsplit, flags);
    }
  };

  k_tin<<<dim3(128, 4, 4), 256, 0, stream>>>(x, X0);

  // ---- TLG branch ----
  k_ln_f2b<<<4096, 256, 0, stream>>>(X0, n1_w, n1_b, XN, 16384);
  conv_gl(XN, tq2, tq_b, Qb, 16384, 128, 128, 0, 3, 3, 4);
  conv_gl(XN, tk2, tk_b, Kb, 16384, 128, 128, 0, 3, 3, 4);
  conv_gl(XN, tv2, tv_b, Vb, 16384, 128, 128, 0, 3, 3, 4);
  k_tlg_attn<<<4096, 256, 0, stream>>>(Qb, Kb, Vb, Yb);
  conv_gl(Yb, tp2, tp_b, X0, 16384, 128, 128, 0, 3, 3, 1);

  // ---- SLG branch ----
  k_ln_f2b<<<4096, 256, 0, stream>>>(X0, n2_w, n2_b, XN, 16384);
  conv_gl(XN, sq2, sq_b, Qb, 16384, 128, 128, 1, 27, 7, 4);
  conv(XN, sc2, sc_b, XC, 8,    128, 128, 1, 27, 2, 2, 2,   4, 16, 16, 16, 4, 8, 8, 8, 4);
  conv(XN, sf2, sf_b, XF, 1024, 128, 128, 1, 27, 8, 8, 8,   4, 16, 16, 16, 2, 2, 2, 2, 4);
  conv(XC, sk2, sk_b, Kf,            8,    128, 128, 1, 27, 2, 2, 2, 1, 2, 2, 2, 1, 1, 1, 1, 0);
  conv(XF, sk2, sk_b, Kf + 8 * 128,  1024, 128, 128, 1, 27, 8, 8, 8, 2, 8, 8, 8, 1, 1, 1, 1, 0);
  conv(XC, sv2, sv_b, Vf,            8,    128, 128, 1, 27, 2, 2, 2, 1, 2, 2, 2, 1, 1, 1, 1, 0);
  conv(XF, sv2, sv_b, Vf + 8 * 128,  1024, 128, 128, 1, 27, 8, 8, 8, 2, 8, 8, 8, 1, 1, 1, 1, 0);
  k_ln_f2b<<<258, 256, 0, stream>>>(Kf, sn_w, sn_b, Kb, 1032);
  k_ln_f2b<<<258, 256, 0, stream>>>(Vf, sn_w, sn_b, Vb, 1032);
  k_pack_kh<<<516, 256, 0, stream>>>(Kb, Kh);
  k_pack_vt<<<516, 256, 0, stream>>>(Vb, Vt);
  k_slg_flash<<<2048, 256, 0, stream>>>(Qb, Kh, Vt, Yb);
  conv_gl(Yb, sp2, sp_b, X0, 16384, 128, 128, 1, 27, 7, 1);

  // ---- MLP branch ----
  k_ln_f2b<<<4096, 256, 0, stream>>>(X0, n3_w, n3_b, XN, 16384);
  conv_gl256(XN, m12, m1_b, H, 16384, 128, 512, 2, 81, 2, 6);
  conv_gl(H, m22, m2_b, X0, 16384, 512, 128, 2, 81, 8, 1);

  k_tout<<<dim3(128, 4, 4), 256, 0, stream>>>(X0, (float*)d_out);
}